// Round 5
// baseline (2241.729 us; speedup 1.0000x reference)
//
#include <hip/hip_runtime.h>
#include <stdint.h>

typedef uint32_t u32;
typedef unsigned long long u64;

#define NEGV (-1e9f)
#define CAP 256
#define SENTINEL 0xFFFFFFFFu

__device__ __forceinline__ u32 f2ord(float f) {
  u32 x = __float_as_uint(f);
  return (x & 0x80000000u) ? ~x : (x | 0x80000000u);
}
__device__ __forceinline__ float ord2f(u32 u) {
  u32 x = (u & 0x80000000u) ? (u ^ 0x80000000u) : ~u;
  return __uint_as_float(x);
}

// ---- mask packer: int32 mask [2][2048][4096] -> u64 bits [2][2048][64] ----
__global__ __launch_bounds__(256)
void pack_mask(const int* __restrict__ mask, u64* __restrict__ mbits) {
  int w = blockIdx.x * 256 + threadIdx.x;
  const int4* p = (const int4*)(mask + (size_t)w * 64);
  u64 bits = 0;
#pragma unroll
  for (int j = 0; j < 16; ++j) {
    int4 m = p[j];
    if (m.x) bits |= 1ull << (j * 4 + 0);
    if (m.y) bits |= 1ull << (j * 4 + 1);
    if (m.z) bits |= 1ull << (j * 4 + 2);
    if (m.w) bits |= 1ull << (j * 4 + 3);
  }
  mbits[w] = bits;
}

// ---- C[M x 512] = A[M x 512] @ W[512 x 512] + bias (row-major out) ----
__global__ __launch_bounds__(256)
void gemm_bias(const float* __restrict__ A, const float* __restrict__ W,
               const float* __restrict__ bias, float* __restrict__ C) {
  __shared__ float As[16][68];
  __shared__ float Bs[16][64];
  const int tid = threadIdx.x;
  const int tx = tid & 15, ty = tid >> 4;
  const int n0 = blockIdx.x << 6, m0 = blockIdx.y << 6;
  float c[4][4] = {};
  for (int k0 = 0; k0 < 512; k0 += 16) {
    {
      const int row = tid >> 2, kp = (tid & 3) << 2;
      float4 av = *(const float4*)&A[(size_t)(m0 + row) * 512 + k0 + kp];
      As[kp + 0][row] = av.x;
      As[kp + 1][row] = av.y;
      As[kp + 2][row] = av.z;
      As[kp + 3][row] = av.w;
      const int kk = tid >> 4, np = (tid & 15) << 2;
      *(float4*)&Bs[kk][np] = *(const float4*)&W[(size_t)(k0 + kk) * 512 + n0 + np];
    }
    __syncthreads();
#pragma unroll
    for (int kk = 0; kk < 16; ++kk) {
      float4 a = *(const float4*)&As[kk][ty << 2];
      float4 b = *(const float4*)&Bs[kk][tx << 2];
      c[0][0] += a.x * b.x; c[0][1] += a.x * b.y; c[0][2] += a.x * b.z; c[0][3] += a.x * b.w;
      c[1][0] += a.y * b.x; c[1][1] += a.y * b.y; c[1][2] += a.y * b.z; c[1][3] += a.y * b.w;
      c[2][0] += a.z * b.x; c[2][1] += a.z * b.y; c[2][2] += a.z * b.z; c[2][3] += a.z * b.w;
      c[3][0] += a.w * b.x; c[3][1] += a.w * b.y; c[3][2] += a.w * b.z; c[3][3] += a.w * b.w;
    }
    __syncthreads();
  }
  float4 bv = *(const float4*)&bias[n0 + (tx << 2)];
#pragma unroll
  for (int i = 0; i < 4; ++i) {
    float4 o;
    o.x = c[i][0] + bv.x; o.y = c[i][1] + bv.y;
    o.z = c[i][2] + bv.z; o.w = c[i][3] + bv.w;
    *(float4*)&C[(size_t)(m0 + (ty << 2) + i) * 512 + n0 + (tx << 2)] = o;
  }
}

// ---- same GEMM math, but stores k-major transposed ----
__global__ __launch_bounds__(256)
void gemm_bias_T(const float* __restrict__ A, const float* __restrict__ W,
                 const float* __restrict__ bias, float* __restrict__ CT, int qsh) {
  __shared__ float As[16][68];
  __shared__ float Bs[16][64];
  const int tid = threadIdx.x;
  const int tx = tid & 15, ty = tid >> 4;
  const int n0 = blockIdx.x << 6, m0 = blockIdx.y << 6;
  float c[4][4] = {};
  for (int k0 = 0; k0 < 512; k0 += 16) {
    {
      const int row = tid >> 2, kp = (tid & 3) << 2;
      float4 av = *(const float4*)&A[(size_t)(m0 + row) * 512 + k0 + kp];
      As[kp + 0][row] = av.x;
      As[kp + 1][row] = av.y;
      As[kp + 2][row] = av.z;
      As[kp + 3][row] = av.w;
      const int kk = tid >> 4, np = (tid & 15) << 2;
      *(float4*)&Bs[kk][np] = *(const float4*)&W[(size_t)(k0 + kk) * 512 + n0 + np];
    }
    __syncthreads();
#pragma unroll
    for (int kk = 0; kk < 16; ++kk) {
      float4 a = *(const float4*)&As[kk][ty << 2];
      float4 b = *(const float4*)&Bs[kk][tx << 2];
      c[0][0] += a.x * b.x; c[0][1] += a.x * b.y; c[0][2] += a.x * b.z; c[0][3] += a.x * b.w;
      c[1][0] += a.y * b.x; c[1][1] += a.y * b.y; c[1][2] += a.y * b.z; c[1][3] += a.y * b.w;
      c[2][0] += a.z * b.x; c[2][1] += a.z * b.y; c[2][2] += a.z * b.z; c[2][3] += a.z * b.w;
      c[3][0] += a.w * b.x; c[3][1] += a.w * b.y; c[3][2] += a.w * b.z; c[3][3] += a.w * b.w;
    }
    __syncthreads();
  }
  float4 bv = *(const float4*)&bias[n0 + (tx << 2)];
  float bvv[4] = {bv.x, bv.y, bv.z, bv.w};
  const int qlen = 1 << qsh;
  const int qmask = qlen - 1;
#pragma unroll
  for (int i = 0; i < 4; ++i) {
#pragma unroll
    for (int j = 0; j < 4; ++j) {
      float val = c[i][j] + bvv[j];
      int m = m0 + (ty << 2) + i;
      int n = n0 + (tx << 2) + j;
      int h = n >> 6, d = n & 63;
      int bb = m >> qsh, q = m & qmask;
      CT[(((size_t)bb * 8 + h) * 64 + d) * qlen + q] = val;
    }
  }
}

// ---- scores: 128(q) x 128(s) tile per block, 8x8 micro, k-major LDS ----
__global__ __launch_bounds__(256)
void score_kernel(const float* __restrict__ qT, const float* __restrict__ kT,
                  const u64* __restrict__ mbits, float* __restrict__ sbuf, int sl0) {
  __shared__ float Qs[64][128];
  __shared__ float Ks[64][128];
  const int sl = sl0 + blockIdx.z;
  const int b = sl >> 3, h = sl & 7;
  const int s0 = blockIdx.x << 7, q0 = blockIdx.y << 7;
  const int tid = threadIdx.x;
  const float* qbase = qT + (size_t)sl * 64 * 2048 + q0;
  const float* kbase = kT + (size_t)h * 64 * 4096 + s0;
  float4* Qf = (float4*)&Qs[0][0];
  float4* Kf = (float4*)&Ks[0][0];
#pragma unroll
  for (int u = 0; u < 8; ++u) {
    int i = (u << 8) + tid;
    int row = i >> 5, col = (i & 31) << 2;
    Qf[i] = *(const float4*)(qbase + (size_t)row * 2048 + col);
    Kf[i] = *(const float4*)(kbase + (size_t)row * 4096 + col);
  }
  __syncthreads();
  const int tx = tid & 15, ty = tid >> 4;
  float c[8][8] = {};
#pragma unroll 4
  for (int g = 0; g < 16; ++g) {
    const int kk = g << 2;
    float qa[8][4], kb[8][4];
#pragma unroll
    for (int t = 0; t < 4; ++t) {
#pragma unroll
      for (int i = 0; i < 8; ++i) qa[i][t] = Qs[kk + t][(ty << 3) + i];
#pragma unroll
      for (int j = 0; j < 4; ++j) {
        kb[j][t]     = Ks[kk + t][(tx << 2) + j];
        kb[4 + j][t] = Ks[kk + t][64 + (tx << 2) + j];
      }
    }
#pragma unroll
    for (int i = 0; i < 8; ++i)
#pragma unroll
      for (int j = 0; j < 8; ++j)
        c[i][j] += qa[i][0] * kb[j][0] + qa[i][1] * kb[j][1]
                 + qa[i][2] * kb[j][2] + qa[i][3] * kb[j][3];
  }
  float* srow = sbuf + ((size_t)blockIdx.z * 2048 + q0) * 4096 + s0;
  const u64* mrow = mbits + ((size_t)(b * 2048 + q0)) * 64 + (s0 >> 6);
#pragma unroll
  for (int i = 0; i < 8; ++i) {
    const int row = (ty << 3) + i;
    u64 wA = mrow[(size_t)row * 64];
    u64 wB = mrow[(size_t)row * 64 + 1];
    float4 o0, o1;
    o0.x = ((wA >> ((tx << 2) + 0)) & 1) ? c[i][0] * 0.125f : NEGV;
    o0.y = ((wA >> ((tx << 2) + 1)) & 1) ? c[i][1] * 0.125f : NEGV;
    o0.z = ((wA >> ((tx << 2) + 2)) & 1) ? c[i][2] * 0.125f : NEGV;
    o0.w = ((wA >> ((tx << 2) + 3)) & 1) ? c[i][3] * 0.125f : NEGV;
    o1.x = ((wB >> ((tx << 2) + 0)) & 1) ? c[i][4] * 0.125f : NEGV;
    o1.y = ((wB >> ((tx << 2) + 1)) & 1) ? c[i][5] * 0.125f : NEGV;
    o1.z = ((wB >> ((tx << 2) + 2)) & 1) ? c[i][6] * 0.125f : NEGV;
    o1.w = ((wB >> ((tx << 2) + 3)) & 1) ? c[i][7] * 0.125f : NEGV;
    *(float4*)&srow[(size_t)row * 4096 + (tx << 2)] = o0;
    *(float4*)&srow[(size_t)row * 4096 + 64 + (tx << 2)] = o1;
  }
}

// ---- K1: streaming candidate filter. One wave per row, 4 waves/block.
// Appends packed (ord<<32 | sidx) for elements >= lo0 (min of per-lane maxes,
// a provable lower bound on the 64th-largest). Writes count (or SENTINEL). ----
__global__ __launch_bounds__(256)
void filter_kernel(const float* __restrict__ sbuf, u64* __restrict__ cand,
                   u32* __restrict__ hdr) {
  const int w = threadIdx.x >> 6, lane = threadIdx.x & 63;
  const int qi = (blockIdx.x << 2) + w;
  const float* srow = sbuf + ((size_t)blockIdx.y * 2048 + qi) * 4096;
  u64* crow = cand + ((size_t)blockIdx.y * 2048 + qi) * CAP;
  const u64 lmask_lt = (1ull << lane) - 1ull;

  float f[64];
#pragma unroll
  for (int j = 0; j < 16; ++j) {
    float4 v = *(const float4*)(srow + (j << 8) + (lane << 2));
    f[j * 4 + 0] = v.x; f[j * 4 + 1] = v.y;
    f[j * 4 + 2] = v.z; f[j * 4 + 3] = v.w;
  }
  float lmax = f[0];
#pragma unroll
  for (int e = 1; e < 64; ++e) lmax = fmaxf(lmax, f[e]);
  float mn = lmax;
#pragma unroll
  for (int off = 32; off; off >>= 1) mn = fminf(mn, __shfl_xor(mn, off, 64));
  const float lo0f = mn;

  int base = 0;
#pragma unroll
  for (int e = 0; e < 64; ++e) {
    bool pred = f[e] >= lo0f;
    u64 m = __ballot(pred);
    if (m != 0ull) {
      int ofs = base + __popcll(m & lmask_lt);
      if (pred && ofs < CAP) {
        int sidx = ((e >> 2) << 8) + (lane << 2) + (e & 3);
        crow[ofs] = ((u64)f2ord(f[e]) << 32) | (u32)sidx;
      }
      base += (int)__popcll(m);
    }
  }
  if (lane == 0) hdr[blockIdx.y * 2048 + qi] = (base <= CAP) ? (u32)base : SENTINEL;
}

// ---- K2: per-row finish from candidates: exact threshold, softmax, V-gather ----
__global__ __launch_bounds__(256)
void finish_kernel(const float* __restrict__ sbuf, const u64* __restrict__ cand,
                   const u32* __restrict__ hdr, const float* __restrict__ vbuf,
                   float* __restrict__ ctxbuf, int sl0) {
  const int sl = sl0 + blockIdx.y;
  const int b = sl >> 3, h = sl & 7;
  const int w = threadIdx.x >> 6, lane = threadIdx.x & 63;
  const int qi = (blockIdx.x << 2) + w;
  __shared__ u64 list_s[4][CAP + 8];
  u64* list = list_s[w];
  const u64 lmask_lt = (1ull << lane) - 1ull;
  const u32 ordneg = f2ord(NEGV);

  const u32 cnt = hdr[blockIdx.y * 2048 + qi];
  float esum = 0.f;
  int nsel = 0;
  bool meanpath = false;

  if (cnt != SENTINEL) {
    const u64* crow = cand + ((size_t)blockIdx.y * 2048 + qi) * CAP;
    u64 c0 = crow[lane * 4 + 0], c1 = crow[lane * 4 + 1];
    u64 c2 = crow[lane * 4 + 2], c3 = crow[lane * 4 + 3];
    u32 n = lane * 4;
    if (n + 0 >= cnt) c0 = 0;
    if (n + 1 >= cnt) c1 = 0;
    if (n + 2 >= cnt) c2 = 0;
    if (n + 3 >= cnt) c3 = 0;
    // wave max / min-nonzero of packed candidates
    u64 mx = c0 > c1 ? c0 : c1;
    u64 t = c2 > c3 ? c2 : c3;
    mx = mx > t ? mx : t;
    u64 z0 = c0 ? c0 : ~0ull, z1 = c1 ? c1 : ~0ull;
    u64 z2 = c2 ? c2 : ~0ull, z3 = c3 ? c3 : ~0ull;
    u64 mnp = z0 < z1 ? z0 : z1;
    u64 t2 = z2 < z3 ? z2 : z3;
    mnp = mnp < t2 ? mnp : t2;
#pragma unroll
    for (int off = 32; off; off >>= 1) {
      u64 a = (u64)__shfl_xor((long long)mx, off, 64);
      u64 bb = (u64)__shfl_xor((long long)mnp, off, 64);
      mx = a > mx ? a : mx;
      mnp = bb < mnp ? bb : mnp;
    }
    u32 lo = (u32)(mnp >> 32), hi = (u32)(mx >> 32) + 1;
    while (hi - lo > 1) {
      u32 mid = lo + ((hi - lo) >> 1);
      u64 mp = (u64)mid << 32;
      int c = __popcll(__ballot(c0 >= mp)) + __popcll(__ballot(c1 >= mp)) +
              __popcll(__ballot(c2 >= mp)) + __popcll(__ballot(c3 >= mp));
      if (c >= 64) lo = mid; else hi = mid;
    }
    const float fm = ord2f((u32)(mx >> 32));
    const u64 tp = (u64)lo << 32;
    int base = 0;
    u64 cj[4] = {c0, c1, c2, c3};
#pragma unroll
    for (int j = 0; j < 4; ++j) {
      bool pred = cj[j] >= tp;
      u64 m = __ballot(pred);
      int ofs = base + __popcll(m & lmask_lt);
      if (pred && ofs < CAP) {
        float ev = __expf(ord2f((u32)(cj[j] >> 32)) - fm);
        list[ofs] = ((u64)((u32)cj[j]) << 32) | (u64)__float_as_uint(ev);
        esum += ev;
      }
      base += (int)__popcll(m);
    }
    nsel = base < CAP ? base : CAP;
  } else {
    // rare fallback: streaming recompute from full score row
    const float* srow = sbuf + ((size_t)blockIdx.y * 2048 + qi) * 4096;
    float lmax = NEGV;
#pragma unroll
    for (int j = 0; j < 16; ++j) {
      float4 v = *(const float4*)(srow + (j << 8) + (lane << 2));
      lmax = fmaxf(fmaxf(fmaxf(lmax, v.x), fmaxf(v.y, v.z)), v.w);
    }
#pragma unroll
    for (int off = 32; off; off >>= 1) lmax = fmaxf(lmax, __shfl_xor(lmax, off, 64));
    const float fm = lmax;
    u32 lo = ordneg, hi = f2ord(fm) + 1;
    while (hi - lo > 1) {
      u32 mid = lo + ((hi - lo) >> 1);
      float midf = ord2f(mid);
      int c = 0;
      for (int j = 0; j < 16; ++j) {
        float4 v = *(const float4*)(srow + (j << 8) + (lane << 2));
        c += __popcll(__ballot(v.x >= midf)) + __popcll(__ballot(v.y >= midf)) +
             __popcll(__ballot(v.z >= midf)) + __popcll(__ballot(v.w >= midf));
      }
      if (c >= 64) lo = mid; else hi = mid;
    }
    const float thrf = ord2f(lo);
    int base = 0;
    for (int j = 0; j < 16; ++j) {
      float4 v = *(const float4*)(srow + (j << 8) + (lane << 2));
      float xs[4] = {v.x, v.y, v.z, v.w};
#pragma unroll
      for (int cpos = 0; cpos < 4; ++cpos) {
        float x = xs[cpos];
        bool pred = (x >= thrf) && (x != NEGV);
        u64 m = __ballot(pred);
        int ofs = base + __popcll(m & lmask_lt);
        if (pred && ofs < CAP) {
          int sidx = (j << 8) + (lane << 2) + cpos;
          float ev = __expf(x - fm);
          list[ofs] = ((u64)(u32)sidx << 32) | (u64)__float_as_uint(ev);
          esum += ev;
        }
        base += (int)__popcll(m);
      }
    }
    nsel = base < CAP ? base : CAP;
    if (base == 0) meanpath = true;  // fully masked row
  }

#pragma unroll
  for (int off = 32; off; off >>= 1) esum += __shfl_xor(esum, off, 64);
  const float* vb = vbuf + h * 64 + lane;
  float outv;
  if (!meanpath) {
    const float rs = 1.0f / esum;
    int pad = (8 - (nsel & 7)) & 7;
    if (lane < pad) list[nsel + lane] = 0;  // ev = +0.0f, idx = 0
    int n8 = nsel + pad;
    float a0 = 0.f, a1 = 0.f, a2 = 0.f, a3 = 0.f;
    float a4 = 0.f, a5 = 0.f, a6 = 0.f, a7 = 0.f;
    for (int g = 0; g < n8; g += 8) {
      u64 p0 = list[g + 0], p1 = list[g + 1], p2 = list[g + 2], p3 = list[g + 3];
      u64 p4 = list[g + 4], p5 = list[g + 5], p6 = list[g + 6], p7 = list[g + 7];
      a0 += __uint_as_float((u32)p0) * vb[(size_t)(p0 >> 32) * 512];
      a1 += __uint_as_float((u32)p1) * vb[(size_t)(p1 >> 32) * 512];
      a2 += __uint_as_float((u32)p2) * vb[(size_t)(p2 >> 32) * 512];
      a3 += __uint_as_float((u32)p3) * vb[(size_t)(p3 >> 32) * 512];
      a4 += __uint_as_float((u32)p4) * vb[(size_t)(p4 >> 32) * 512];
      a5 += __uint_as_float((u32)p5) * vb[(size_t)(p5 >> 32) * 512];
      a6 += __uint_as_float((u32)p6) * vb[(size_t)(p6 >> 32) * 512];
      a7 += __uint_as_float((u32)p7) * vb[(size_t)(p7 >> 32) * 512];
    }
    outv = (((a0 + a1) + (a2 + a3)) + ((a4 + a5) + (a6 + a7))) * rs;
  } else {
    float acc = 0.f;
    for (int s = 0; s < 4096; ++s) acc += vb[(size_t)s * 512];
    outv = acc * (1.0f / 4096.0f);
  }
  ctxbuf[((size_t)(b * 2048 + qi)) * 512 + h * 64 + lane] = outv;
}

extern "C" void kernel_launch(void* const* d_in, const int* in_sizes, int n_in,
                              void* d_out, int out_size, void* d_ws, size_t ws_size,
                              hipStream_t stream) {
  const float* main_in = (const float*)d_in[0];
  const float* side_in = (const float*)d_in[1];
  const int*   mask    = (const int*)d_in[2];
  const float* Wq = (const float*)d_in[3];
  const float* bq = (const float*)d_in[4];
  const float* Wk = (const float*)d_in[5];
  const float* bk = (const float*)d_in[6];
  const float* Wv = (const float*)d_in[7];
  const float* bv = (const float*)d_in[8];
  const float* Wo = (const float*)d_in[9];
  const float* bo = (const float*)d_in[10];
  float* out = (float*)d_out;

  char* ws = (char*)d_ws;
  float* qT   = (float*)(ws);                       // 8 MB
  float* kT   = (float*)(ws + ((size_t)8 << 20));   // 8 MB
  float* vbuf = (float*)(ws + ((size_t)16 << 20));  // 8 MB
  float* ctxb = (float*)(ws + ((size_t)24 << 20));  // 8 MB
  u64* mbits  = (u64*)(ws + ((size_t)32 << 20));    // 2 MB
  const size_t base = (size_t)34 << 20;
  const size_t sliceb = (size_t)2048 * 4096 * 4;            // 32 MB scores/slice
  const size_t candb  = (size_t)2048 * CAP * 8;             // 4 MB cands/slice
  const size_t hdrb   = (size_t)64 << 10;                   // 64 KB hdr/slice
  const size_t per = sliceb + candb + hdrb;

  int nz = 1;
  if (ws_size > base + per) {
    size_t m = (ws_size - base) / per;
    nz = (int)(m > 16 ? 16 : m);
  }
  float* sbuf = (float*)(ws + base);
  u64*   cand = (u64*)(ws + base + (size_t)nz * sliceb);
  u32*   hdr  = (u32*)(ws + base + (size_t)nz * (sliceb + candb));

  pack_mask<<<1024, 256, 0, stream>>>(mask, mbits);
  gemm_bias_T<<<dim3(8, 64), 256, 0, stream>>>(main_in, Wq, bq, qT, 11);
  gemm_bias_T<<<dim3(8, 64), 256, 0, stream>>>(side_in, Wk, bk, kT, 12);
  gemm_bias  <<<dim3(8, 64), 256, 0, stream>>>(side_in, Wv, bv, vbuf);

  for (int sl0 = 0; sl0 < 16; sl0 += nz) {
    int z = nz < (16 - sl0) ? nz : (16 - sl0);
    score_kernel <<<dim3(32, 16, z), 256, 0, stream>>>(qT, kT, mbits, sbuf, sl0);
    filter_kernel<<<dim3(512, z), 256, 0, stream>>>(sbuf, cand, hdr);
    finish_kernel<<<dim3(512, z), 256, 0, stream>>>(sbuf, cand, hdr, vbuf, ctxb, sl0);
  }

  gemm_bias<<<dim3(8, 64), 256, 0, stream>>>(ctxb, Wo, bo, out);
}

// Round 6
// 1222.843 us; speedup vs baseline: 1.8332x; 1.8332x over previous
//
#include <hip/hip_runtime.h>
#include <stdint.h>

typedef uint32_t u32;
typedef unsigned long long u64;

#define NEGV (-1e9f)
#define CAP 1024
#define LISTCAP 256
#define SENTINEL 0xFFFFFFFFu

__device__ __forceinline__ u32 f2ord(float f) {
  u32 x = __float_as_uint(f);
  return (x & 0x80000000u) ? ~x : (x | 0x80000000u);
}
__device__ __forceinline__ float ord2f(u32 u) {
  u32 x = (u & 0x80000000u) ? (u ^ 0x80000000u) : ~u;
  return __uint_as_float(x);
}

// ---- mask packer: int32 mask [2][2048][4096] -> u64 bits [2][2048][64] ----
__global__ __launch_bounds__(256)
void pack_mask(const int* __restrict__ mask, u64* __restrict__ mbits) {
  int w = blockIdx.x * 256 + threadIdx.x;
  const int4* p = (const int4*)(mask + (size_t)w * 64);
  u64 bits = 0;
#pragma unroll
  for (int j = 0; j < 16; ++j) {
    int4 m = p[j];
    if (m.x) bits |= 1ull << (j * 4 + 0);
    if (m.y) bits |= 1ull << (j * 4 + 1);
    if (m.z) bits |= 1ull << (j * 4 + 2);
    if (m.w) bits |= 1ull << (j * 4 + 3);
  }
  mbits[w] = bits;
}

// ---- C[M x 512] = A[M x 512] @ W[512 x 512] + bias (row-major out) ----
__global__ __launch_bounds__(256)
void gemm_bias(const float* __restrict__ A, const float* __restrict__ W,
               const float* __restrict__ bias, float* __restrict__ C) {
  __shared__ float As[16][68];
  __shared__ float Bs[16][64];
  const int tid = threadIdx.x;
  const int tx = tid & 15, ty = tid >> 4;
  const int n0 = blockIdx.x << 6, m0 = blockIdx.y << 6;
  float c[4][4] = {};
  for (int k0 = 0; k0 < 512; k0 += 16) {
    {
      const int row = tid >> 2, kp = (tid & 3) << 2;
      float4 av = *(const float4*)&A[(size_t)(m0 + row) * 512 + k0 + kp];
      As[kp + 0][row] = av.x;
      As[kp + 1][row] = av.y;
      As[kp + 2][row] = av.z;
      As[kp + 3][row] = av.w;
      const int kk = tid >> 4, np = (tid & 15) << 2;
      *(float4*)&Bs[kk][np] = *(const float4*)&W[(size_t)(k0 + kk) * 512 + n0 + np];
    }
    __syncthreads();
#pragma unroll
    for (int kk = 0; kk < 16; ++kk) {
      float4 a = *(const float4*)&As[kk][ty << 2];
      float4 b = *(const float4*)&Bs[kk][tx << 2];
      c[0][0] += a.x * b.x; c[0][1] += a.x * b.y; c[0][2] += a.x * b.z; c[0][3] += a.x * b.w;
      c[1][0] += a.y * b.x; c[1][1] += a.y * b.y; c[1][2] += a.y * b.z; c[1][3] += a.y * b.w;
      c[2][0] += a.z * b.x; c[2][1] += a.z * b.y; c[2][2] += a.z * b.z; c[2][3] += a.z * b.w;
      c[3][0] += a.w * b.x; c[3][1] += a.w * b.y; c[3][2] += a.w * b.z; c[3][3] += a.w * b.w;
    }
    __syncthreads();
  }
  float4 bv = *(const float4*)&bias[n0 + (tx << 2)];
#pragma unroll
  for (int i = 0; i < 4; ++i) {
    float4 o;
    o.x = c[i][0] + bv.x; o.y = c[i][1] + bv.y;
    o.z = c[i][2] + bv.z; o.w = c[i][3] + bv.w;
    *(float4*)&C[(size_t)(m0 + (ty << 2) + i) * 512 + n0 + (tx << 2)] = o;
  }
}

// ---- same GEMM math, but stores k-major transposed ----
__global__ __launch_bounds__(256)
void gemm_bias_T(const float* __restrict__ A, const float* __restrict__ W,
                 const float* __restrict__ bias, float* __restrict__ CT, int qsh) {
  __shared__ float As[16][68];
  __shared__ float Bs[16][64];
  const int tid = threadIdx.x;
  const int tx = tid & 15, ty = tid >> 4;
  const int n0 = blockIdx.x << 6, m0 = blockIdx.y << 6;
  float c[4][4] = {};
  for (int k0 = 0; k0 < 512; k0 += 16) {
    {
      const int row = tid >> 2, kp = (tid & 3) << 2;
      float4 av = *(const float4*)&A[(size_t)(m0 + row) * 512 + k0 + kp];
      As[kp + 0][row] = av.x;
      As[kp + 1][row] = av.y;
      As[kp + 2][row] = av.z;
      As[kp + 3][row] = av.w;
      const int kk = tid >> 4, np = (tid & 15) << 2;
      *(float4*)&Bs[kk][np] = *(const float4*)&W[(size_t)(k0 + kk) * 512 + n0 + np];
    }
    __syncthreads();
#pragma unroll
    for (int kk = 0; kk < 16; ++kk) {
      float4 a = *(const float4*)&As[kk][ty << 2];
      float4 b = *(const float4*)&Bs[kk][tx << 2];
      c[0][0] += a.x * b.x; c[0][1] += a.x * b.y; c[0][2] += a.x * b.z; c[0][3] += a.x * b.w;
      c[1][0] += a.y * b.x; c[1][1] += a.y * b.y; c[1][2] += a.y * b.z; c[1][3] += a.y * b.w;
      c[2][0] += a.z * b.x; c[2][1] += a.z * b.y; c[2][2] += a.z * b.z; c[2][3] += a.z * b.w;
      c[3][0] += a.w * b.x; c[3][1] += a.w * b.y; c[3][2] += a.w * b.z; c[3][3] += a.w * b.w;
    }
    __syncthreads();
  }
  float4 bv = *(const float4*)&bias[n0 + (tx << 2)];
  float bvv[4] = {bv.x, bv.y, bv.z, bv.w};
  const int qlen = 1 << qsh;
  const int qmask = qlen - 1;
#pragma unroll
  for (int i = 0; i < 4; ++i) {
#pragma unroll
    for (int j = 0; j < 4; ++j) {
      float val = c[i][j] + bvv[j];
      int m = m0 + (ty << 2) + i;
      int n = n0 + (tx << 2) + j;
      int h = n >> 6, d = n & 63;
      int bb = m >> qsh, q = m & qmask;
      CT[(((size_t)bb * 8 + h) * 64 + d) * qlen + q] = val;
    }
  }
}

// ---- scores: 128(q) x 128(s) tile per block, 8x8 micro, k-major LDS ----
__global__ __launch_bounds__(256)
void score_kernel(const float* __restrict__ qT, const float* __restrict__ kT,
                  const u64* __restrict__ mbits, float* __restrict__ sbuf, int sl0) {
  __shared__ float Qs[64][128];
  __shared__ float Ks[64][128];
  const int sl = sl0 + blockIdx.z;
  const int b = sl >> 3, h = sl & 7;
  const int s0 = blockIdx.x << 7, q0 = blockIdx.y << 7;
  const int tid = threadIdx.x;
  const float* qbase = qT + (size_t)sl * 64 * 2048 + q0;
  const float* kbase = kT + (size_t)h * 64 * 4096 + s0;
  float4* Qf = (float4*)&Qs[0][0];
  float4* Kf = (float4*)&Ks[0][0];
#pragma unroll
  for (int u = 0; u < 8; ++u) {
    int i = (u << 8) + tid;
    int row = i >> 5, col = (i & 31) << 2;
    Qf[i] = *(const float4*)(qbase + (size_t)row * 2048 + col);
    Kf[i] = *(const float4*)(kbase + (size_t)row * 4096 + col);
  }
  __syncthreads();
  const int tx = tid & 15, ty = tid >> 4;
  float c[8][8] = {};
#pragma unroll 4
  for (int g = 0; g < 16; ++g) {
    const int kk = g << 2;
    float qa[8][4], kb[8][4];
#pragma unroll
    for (int t = 0; t < 4; ++t) {
#pragma unroll
      for (int i = 0; i < 8; ++i) qa[i][t] = Qs[kk + t][(ty << 3) + i];
#pragma unroll
      for (int j = 0; j < 4; ++j) {
        kb[j][t]     = Ks[kk + t][(tx << 2) + j];
        kb[4 + j][t] = Ks[kk + t][64 + (tx << 2) + j];
      }
    }
#pragma unroll
    for (int i = 0; i < 8; ++i)
#pragma unroll
      for (int j = 0; j < 8; ++j)
        c[i][j] += qa[i][0] * kb[j][0] + qa[i][1] * kb[j][1]
                 + qa[i][2] * kb[j][2] + qa[i][3] * kb[j][3];
  }
  float* srow = sbuf + ((size_t)blockIdx.z * 2048 + q0) * 4096 + s0;
  const u64* mrow = mbits + ((size_t)(b * 2048 + q0)) * 64 + (s0 >> 6);
#pragma unroll
  for (int i = 0; i < 8; ++i) {
    const int row = (ty << 3) + i;
    u64 wA = mrow[(size_t)row * 64];
    u64 wB = mrow[(size_t)row * 64 + 1];
    float4 o0, o1;
    o0.x = ((wA >> ((tx << 2) + 0)) & 1) ? c[i][0] * 0.125f : NEGV;
    o0.y = ((wA >> ((tx << 2) + 1)) & 1) ? c[i][1] * 0.125f : NEGV;
    o0.z = ((wA >> ((tx << 2) + 2)) & 1) ? c[i][2] * 0.125f : NEGV;
    o0.w = ((wA >> ((tx << 2) + 3)) & 1) ? c[i][3] * 0.125f : NEGV;
    o1.x = ((wB >> ((tx << 2) + 0)) & 1) ? c[i][4] * 0.125f : NEGV;
    o1.y = ((wB >> ((tx << 2) + 1)) & 1) ? c[i][5] * 0.125f : NEGV;
    o1.z = ((wB >> ((tx << 2) + 2)) & 1) ? c[i][6] * 0.125f : NEGV;
    o1.w = ((wB >> ((tx << 2) + 3)) & 1) ? c[i][7] * 0.125f : NEGV;
    *(float4*)&srow[(size_t)row * 4096 + (tx << 2)] = o0;
    *(float4*)&srow[(size_t)row * 4096 + 64 + (tx << 2)] = o1;
  }
}

// ---- K1: streaming candidate filter. One wave per row, 4 waves/block.
// Candidates = elements >= lo0 (min of per-lane maxes, provable lower bound on
// the 64th-largest). Scan-based compaction, lane-major order (order-free). ----
__global__ __launch_bounds__(256)
void filter_kernel(const float* __restrict__ sbuf, u64* __restrict__ cand,
                   u32* __restrict__ hdr) {
  const int w = threadIdx.x >> 6, lane = threadIdx.x & 63;
  const int qi = (blockIdx.x << 2) + w;
  const float* srow = sbuf + ((size_t)blockIdx.y * 2048 + qi) * 4096;
  u64* crow = cand + ((size_t)blockIdx.y * 2048 + qi) * CAP;

  float f[64];
#pragma unroll
  for (int j = 0; j < 16; ++j) {
    float4 v = *(const float4*)(srow + (j << 8) + (lane << 2));
    f[j * 4 + 0] = v.x; f[j * 4 + 1] = v.y;
    f[j * 4 + 2] = v.z; f[j * 4 + 3] = v.w;
  }
  float lmax = f[0];
#pragma unroll
  for (int e = 1; e < 64; ++e) lmax = fmaxf(lmax, f[e]);
  float mn = lmax;
#pragma unroll
  for (int off = 32; off; off >>= 1) mn = fminf(mn, __shfl_xor(mn, off, 64));
  const float lo0f = mn;

  // per-lane candidate count
  int cnt = 0;
#pragma unroll
  for (int e = 0; e < 64; ++e) cnt += (f[e] >= lo0f) ? 1 : 0;
  // inclusive scan across the wave
  int inc = cnt;
#pragma unroll
  for (int off = 1; off < 64; off <<= 1) {
    int t = __shfl_up(inc, off, 64);
    if (lane >= off) inc += t;
  }
  const int total = __shfl(inc, 63, 64);
  int ofs = inc - cnt;
  if (total <= CAP) {
#pragma unroll
    for (int e = 0; e < 64; ++e) {
      if (f[e] >= lo0f) {
        int sidx = ((e >> 2) << 8) + (lane << 2) + (e & 3);
        crow[ofs++] = ((u64)f2ord(f[e]) << 32) | (u32)sidx;
      }
    }
  }
  if (lane == 0) hdr[blockIdx.y * 2048 + qi] = (total <= CAP) ? (u32)total : SENTINEL;
}

// ---- K2: per-row finish from candidates: exact threshold, softmax, V-gather ----
__global__ __launch_bounds__(256)
void finish_kernel(const float* __restrict__ sbuf, const u64* __restrict__ cand,
                   const u32* __restrict__ hdr, const float* __restrict__ vbuf,
                   float* __restrict__ ctxbuf, int sl0) {
  const int sl = sl0 + blockIdx.y;
  const int b = sl >> 3, h = sl & 7;
  const int w = threadIdx.x >> 6, lane = threadIdx.x & 63;
  const int qi = (blockIdx.x << 2) + w;
  __shared__ u64 list_s[4][LISTCAP + 8];
  u64* list = list_s[w];
  const u64 lmask_lt = (1ull << lane) - 1ull;
  const u32 ordneg = f2ord(NEGV);

  const u32 cnt = hdr[blockIdx.y * 2048 + qi];
  float esum = 0.f;
  int nsel = 0;
  bool meanpath = false;

  if (cnt != SENTINEL) {
    const u64* crow = cand + ((size_t)blockIdx.y * 2048 + qi) * CAP;
    const int ngrp = (int)((cnt + 63) >> 6);  // wave-uniform, <= 16
    u64 cj[16];
#pragma unroll
    for (int j = 0; j < 16; ++j) {
      cj[j] = 0;
      if (j < ngrp) {
        u32 n = (u32)lane + ((u32)j << 6);
        cj[j] = (n < cnt) ? crow[n] : 0;
      }
    }
    // wave max / min-nonzero over candidates
    u64 mx = 0, mnp = ~0ull;
#pragma unroll
    for (int j = 0; j < 16; ++j) {
      if (j < ngrp) {
        u64 v = cj[j];
        mx = v > mx ? v : mx;
        u64 z = v ? v : ~0ull;
        mnp = z < mnp ? z : mnp;
      }
    }
#pragma unroll
    for (int off = 32; off; off >>= 1) {
      u64 a = (u64)__shfl_xor((long long)mx, off, 64);
      u64 bb = (u64)__shfl_xor((long long)mnp, off, 64);
      mx = a > mx ? a : mx;
      mnp = bb < mnp ? bb : mnp;
    }
    u32 lo = (u32)(mnp >> 32), hi = (u32)(mx >> 32) + 1;
    while (hi - lo > 1) {
      u32 mid = lo + ((hi - lo) >> 1);
      u64 mp = (u64)mid << 32;
      int c = 0;
#pragma unroll
      for (int j = 0; j < 16; ++j)
        if (j < ngrp) c += __popcll(__ballot(cj[j] >= mp));
      if (c >= 64) lo = mid; else hi = mid;
    }
    const float fm = ord2f((u32)(mx >> 32));
    const u64 tp = (u64)lo << 32;
    int base = 0;
#pragma unroll
    for (int j = 0; j < 16; ++j) {
      if (j < ngrp) {
        bool pred = cj[j] >= tp;
        u64 m = __ballot(pred);
        int ofs = base + __popcll(m & lmask_lt);
        if (pred && ofs < LISTCAP) {
          float ev = __expf(ord2f((u32)(cj[j] >> 32)) - fm);
          list[ofs] = ((u64)((u32)cj[j]) << 32) | (u64)__float_as_uint(ev);
          esum += ev;
        }
        base += (int)__popcll(m);
      }
    }
    nsel = base < LISTCAP ? base : LISTCAP;
  } else {
    // rare fallback: streaming recompute from full score row (exact)
    const float* srow = sbuf + ((size_t)blockIdx.y * 2048 + qi) * 4096;
    float lmax = NEGV;
#pragma unroll
    for (int j = 0; j < 16; ++j) {
      float4 v = *(const float4*)(srow + (j << 8) + (lane << 2));
      lmax = fmaxf(fmaxf(fmaxf(lmax, v.x), fmaxf(v.y, v.z)), v.w);
    }
#pragma unroll
    for (int off = 32; off; off >>= 1) lmax = fmaxf(lmax, __shfl_xor(lmax, off, 64));
    const float fm = lmax;
    u32 lo = ordneg, hi = f2ord(fm) + 1;
    while (hi - lo > 1) {
      u32 mid = lo + ((hi - lo) >> 1);
      float midf = ord2f(mid);
      int c = 0;
      for (int j = 0; j < 16; ++j) {
        float4 v = *(const float4*)(srow + (j << 8) + (lane << 2));
        c += __popcll(__ballot(v.x >= midf)) + __popcll(__ballot(v.y >= midf)) +
             __popcll(__ballot(v.z >= midf)) + __popcll(__ballot(v.w >= midf));
      }
      if (c >= 64) lo = mid; else hi = mid;
    }
    const float thrf = ord2f(lo);
    int base = 0;
    for (int j = 0; j < 16; ++j) {
      float4 v = *(const float4*)(srow + (j << 8) + (lane << 2));
      float xs[4] = {v.x, v.y, v.z, v.w};
#pragma unroll
      for (int cpos = 0; cpos < 4; ++cpos) {
        float x = xs[cpos];
        bool pred = (x >= thrf) && (x != NEGV);
        u64 m = __ballot(pred);
        int ofs = base + __popcll(m & lmask_lt);
        if (pred && ofs < LISTCAP) {
          int sidx = (j << 8) + (lane << 2) + cpos;
          float ev = __expf(x - fm);
          list[ofs] = ((u64)(u32)sidx << 32) | (u64)__float_as_uint(ev);
          esum += ev;
        }
        base += (int)__popcll(m);
      }
    }
    nsel = base < LISTCAP ? base : LISTCAP;
    if (base == 0) meanpath = true;  // fully masked row
  }

#pragma unroll
  for (int off = 32; off; off >>= 1) esum += __shfl_xor(esum, off, 64);
  const float* vb = vbuf + h * 64 + lane;
  float outv;
  if (!meanpath) {
    const float rs = 1.0f / esum;
    int pad = (8 - (nsel & 7)) & 7;
    if (lane < pad) list[nsel + lane] = 0;  // ev = +0.0f, idx = 0
    int n8 = nsel + pad;
    float a0 = 0.f, a1 = 0.f, a2 = 0.f, a3 = 0.f;
    float a4 = 0.f, a5 = 0.f, a6 = 0.f, a7 = 0.f;
    for (int g = 0; g < n8; g += 8) {
      u64 p0 = list[g + 0], p1 = list[g + 1], p2 = list[g + 2], p3 = list[g + 3];
      u64 p4 = list[g + 4], p5 = list[g + 5], p6 = list[g + 6], p7 = list[g + 7];
      a0 += __uint_as_float((u32)p0) * vb[(size_t)(p0 >> 32) * 512];
      a1 += __uint_as_float((u32)p1) * vb[(size_t)(p1 >> 32) * 512];
      a2 += __uint_as_float((u32)p2) * vb[(size_t)(p2 >> 32) * 512];
      a3 += __uint_as_float((u32)p3) * vb[(size_t)(p3 >> 32) * 512];
      a4 += __uint_as_float((u32)p4) * vb[(size_t)(p4 >> 32) * 512];
      a5 += __uint_as_float((u32)p5) * vb[(size_t)(p5 >> 32) * 512];
      a6 += __uint_as_float((u32)p6) * vb[(size_t)(p6 >> 32) * 512];
      a7 += __uint_as_float((u32)p7) * vb[(size_t)(p7 >> 32) * 512];
    }
    outv = (((a0 + a1) + (a2 + a3)) + ((a4 + a5) + (a6 + a7))) * rs;
  } else {
    float acc = 0.f;
    for (int s = 0; s < 4096; ++s) acc += vb[(size_t)s * 512];
    outv = acc * (1.0f / 4096.0f);
  }
  ctxbuf[((size_t)(b * 2048 + qi)) * 512 + h * 64 + lane] = outv;
}

extern "C" void kernel_launch(void* const* d_in, const int* in_sizes, int n_in,
                              void* d_out, int out_size, void* d_ws, size_t ws_size,
                              hipStream_t stream) {
  const float* main_in = (const float*)d_in[0];
  const float* side_in = (const float*)d_in[1];
  const int*   mask    = (const int*)d_in[2];
  const float* Wq = (const float*)d_in[3];
  const float* bq = (const float*)d_in[4];
  const float* Wk = (const float*)d_in[5];
  const float* bk = (const float*)d_in[6];
  const float* Wv = (const float*)d_in[7];
  const float* bv = (const float*)d_in[8];
  const float* Wo = (const float*)d_in[9];
  const float* bo = (const float*)d_in[10];
  float* out = (float*)d_out;

  char* ws = (char*)d_ws;
  float* qT   = (float*)(ws);                       // 8 MB
  float* kT   = (float*)(ws + ((size_t)8 << 20));   // 8 MB
  float* vbuf = (float*)(ws + ((size_t)16 << 20));  // 8 MB
  float* ctxb = (float*)(ws + ((size_t)24 << 20));  // 8 MB
  u64* mbits  = (u64*)(ws + ((size_t)32 << 20));    // 2 MB
  const size_t base = (size_t)34 << 20;
  const size_t sliceb = (size_t)2048 * 4096 * 4;            // 32 MB scores/slice
  const size_t candb  = (size_t)2048 * CAP * 8;             // 16 MB cands/slice
  const size_t hdrb   = (size_t)64 << 10;                   // 64 KB hdr/slice
  const size_t per = sliceb + candb + hdrb;

  int nz = 1;
  if (ws_size > base + per) {
    size_t m = (ws_size - base) / per;
    nz = (int)(m > 16 ? 16 : m);
  }
  float* sbuf = (float*)(ws + base);
  u64*   cand = (u64*)(ws + base + (size_t)nz * sliceb);
  u32*   hdr  = (u32*)(ws + base + (size_t)nz * (sliceb + candb));

  pack_mask<<<1024, 256, 0, stream>>>(mask, mbits);
  gemm_bias_T<<<dim3(8, 64), 256, 0, stream>>>(main_in, Wq, bq, qT, 11);
  gemm_bias_T<<<dim3(8, 64), 256, 0, stream>>>(side_in, Wk, bk, kT, 12);
  gemm_bias  <<<dim3(8, 64), 256, 0, stream>>>(side_in, Wv, bv, vbuf);

  for (int sl0 = 0; sl0 < 16; sl0 += nz) {
    int z = nz < (16 - sl0) ? nz : (16 - sl0);
    score_kernel <<<dim3(32, 16, z), 256, 0, stream>>>(qT, kT, mbits, sbuf, sl0);
    filter_kernel<<<dim3(512, z), 256, 0, stream>>>(sbuf, cand, hdr);
    finish_kernel<<<dim3(512, z), 256, 0, stream>>>(sbuf, cand, hdr, vbuf, ctxb, sl0);
  }

  gemm_bias<<<dim3(8, 64), 256, 0, stream>>>(ctxb, Wo, bo, out);
}

// Round 7
// 819.578 us; speedup vs baseline: 2.7352x; 1.4920x over previous
//
#include <hip/hip_runtime.h>
#include <stdint.h>

typedef uint32_t u32;
typedef unsigned long long u64;

#define NEGV (-1e9f)
#define NCAND 16
#define LISTCAP 256

__device__ __forceinline__ u32 f2ord(float f) {
  u32 x = __float_as_uint(f);
  return (x & 0x80000000u) ? ~x : (x | 0x80000000u);
}
__device__ __forceinline__ float ord2f(u32 u) {
  u32 x = (u & 0x80000000u) ? (u ^ 0x80000000u) : ~u;
  return __uint_as_float(x);
}

// ---- mask packer: int32 mask [2][2048][4096] -> u64 bits [2][2048][64] ----
__global__ __launch_bounds__(256)
void pack_mask(const int* __restrict__ mask, u64* __restrict__ mbits) {
  int w = blockIdx.x * 256 + threadIdx.x;
  const int4* p = (const int4*)(mask + (size_t)w * 64);
  u64 bits = 0;
#pragma unroll
  for (int j = 0; j < 16; ++j) {
    int4 m = p[j];
    if (m.x) bits |= 1ull << (j * 4 + 0);
    if (m.y) bits |= 1ull << (j * 4 + 1);
    if (m.z) bits |= 1ull << (j * 4 + 2);
    if (m.w) bits |= 1ull << (j * 4 + 3);
  }
  mbits[w] = bits;
}

// ---- C[M x 512] = A[M x 512] @ W[512 x 512] + bias (row-major out) ----
__global__ __launch_bounds__(256)
void gemm_bias(const float* __restrict__ A, const float* __restrict__ W,
               const float* __restrict__ bias, float* __restrict__ C) {
  __shared__ float As[16][68];
  __shared__ float Bs[16][64];
  const int tid = threadIdx.x;
  const int tx = tid & 15, ty = tid >> 4;
  const int n0 = blockIdx.x << 6, m0 = blockIdx.y << 6;
  float c[4][4] = {};
  for (int k0 = 0; k0 < 512; k0 += 16) {
    {
      const int row = tid >> 2, kp = (tid & 3) << 2;
      float4 av = *(const float4*)&A[(size_t)(m0 + row) * 512 + k0 + kp];
      As[kp + 0][row] = av.x;
      As[kp + 1][row] = av.y;
      As[kp + 2][row] = av.z;
      As[kp + 3][row] = av.w;
      const int kk = tid >> 4, np = (tid & 15) << 2;
      *(float4*)&Bs[kk][np] = *(const float4*)&W[(size_t)(k0 + kk) * 512 + n0 + np];
    }
    __syncthreads();
#pragma unroll
    for (int kk = 0; kk < 16; ++kk) {
      float4 a = *(const float4*)&As[kk][ty << 2];
      float4 b = *(const float4*)&Bs[kk][tx << 2];
      c[0][0] += a.x * b.x; c[0][1] += a.x * b.y; c[0][2] += a.x * b.z; c[0][3] += a.x * b.w;
      c[1][0] += a.y * b.x; c[1][1] += a.y * b.y; c[1][2] += a.y * b.z; c[1][3] += a.y * b.w;
      c[2][0] += a.z * b.x; c[2][1] += a.z * b.y; c[2][2] += a.z * b.z; c[2][3] += a.z * b.w;
      c[3][0] += a.w * b.x; c[3][1] += a.w * b.y; c[3][2] += a.w * b.z; c[3][3] += a.w * b.w;
    }
    __syncthreads();
  }
  float4 bv = *(const float4*)&bias[n0 + (tx << 2)];
#pragma unroll
  for (int i = 0; i < 4; ++i) {
    float4 o;
    o.x = c[i][0] + bv.x; o.y = c[i][1] + bv.y;
    o.z = c[i][2] + bv.z; o.w = c[i][3] + bv.w;
    *(float4*)&C[(size_t)(m0 + (ty << 2) + i) * 512 + n0 + (tx << 2)] = o;
  }
}

// ---- same GEMM math, but stores k-major transposed ----
__global__ __launch_bounds__(256)
void gemm_bias_T(const float* __restrict__ A, const float* __restrict__ W,
                 const float* __restrict__ bias, float* __restrict__ CT, int qsh) {
  __shared__ float As[16][68];
  __shared__ float Bs[16][64];
  const int tid = threadIdx.x;
  const int tx = tid & 15, ty = tid >> 4;
  const int n0 = blockIdx.x << 6, m0 = blockIdx.y << 6;
  float c[4][4] = {};
  for (int k0 = 0; k0 < 512; k0 += 16) {
    {
      const int row = tid >> 2, kp = (tid & 3) << 2;
      float4 av = *(const float4*)&A[(size_t)(m0 + row) * 512 + k0 + kp];
      As[kp + 0][row] = av.x;
      As[kp + 1][row] = av.y;
      As[kp + 2][row] = av.z;
      As[kp + 3][row] = av.w;
      const int kk = tid >> 4, np = (tid & 15) << 2;
      *(float4*)&Bs[kk][np] = *(const float4*)&W[(size_t)(k0 + kk) * 512 + n0 + np];
    }
    __syncthreads();
#pragma unroll
    for (int kk = 0; kk < 16; ++kk) {
      float4 a = *(const float4*)&As[kk][ty << 2];
      float4 b = *(const float4*)&Bs[kk][tx << 2];
      c[0][0] += a.x * b.x; c[0][1] += a.x * b.y; c[0][2] += a.x * b.z; c[0][3] += a.x * b.w;
      c[1][0] += a.y * b.x; c[1][1] += a.y * b.y; c[1][2] += a.y * b.z; c[1][3] += a.y * b.w;
      c[2][0] += a.z * b.x; c[2][1] += a.z * b.y; c[2][2] += a.z * b.z; c[2][3] += a.z * b.w;
      c[3][0] += a.w * b.x; c[3][1] += a.w * b.y; c[3][2] += a.w * b.z; c[3][3] += a.w * b.w;
    }
    __syncthreads();
  }
  float4 bv = *(const float4*)&bias[n0 + (tx << 2)];
  float bvv[4] = {bv.x, bv.y, bv.z, bv.w};
  const int qlen = 1 << qsh;
  const int qmask = qlen - 1;
#pragma unroll
  for (int i = 0; i < 4; ++i) {
#pragma unroll
    for (int j = 0; j < 4; ++j) {
      float val = c[i][j] + bvv[j];
      int m = m0 + (ty << 2) + i;
      int n = n0 + (tx << 2) + j;
      int h = n >> 6, d = n & 63;
      int bb = m >> qsh, q = m & qmask;
      CT[(((size_t)bb * 8 + h) * 64 + d) * qlen + q] = val;
    }
  }
}

// ---- scores: 128(q) x 128(s) tile per block, 8x8 micro, k-major LDS.
// Also emits per-row 64-wide-segment maxes of the MASKED scores. ----
__global__ __launch_bounds__(256)
void score_kernel(const float* __restrict__ qT, const float* __restrict__ kT,
                  const u64* __restrict__ mbits, float* __restrict__ sbuf,
                  float* __restrict__ segmax, int sl0) {
  __shared__ float Qs[64][128];
  __shared__ float Ks[64][128];
  const int sl = sl0 + blockIdx.z;
  const int b = sl >> 3, h = sl & 7;
  const int s0 = blockIdx.x << 7, q0 = blockIdx.y << 7;
  const int tid = threadIdx.x;
  const float* qbase = qT + (size_t)sl * 64 * 2048 + q0;
  const float* kbase = kT + (size_t)h * 64 * 4096 + s0;
  float4* Qf = (float4*)&Qs[0][0];
  float4* Kf = (float4*)&Ks[0][0];
#pragma unroll
  for (int u = 0; u < 8; ++u) {
    int i = (u << 8) + tid;
    int row = i >> 5, col = (i & 31) << 2;
    Qf[i] = *(const float4*)(qbase + (size_t)row * 2048 + col);
    Kf[i] = *(const float4*)(kbase + (size_t)row * 4096 + col);
  }
  __syncthreads();
  const int tx = tid & 15, ty = tid >> 4;
  float c[8][8] = {};
#pragma unroll 4
  for (int g = 0; g < 16; ++g) {
    const int kk = g << 2;
    float qa[8][4], kb[8][4];
#pragma unroll
    for (int t = 0; t < 4; ++t) {
#pragma unroll
      for (int i = 0; i < 8; ++i) qa[i][t] = Qs[kk + t][(ty << 3) + i];
#pragma unroll
      for (int j = 0; j < 4; ++j) {
        kb[j][t]     = Ks[kk + t][(tx << 2) + j];
        kb[4 + j][t] = Ks[kk + t][64 + (tx << 2) + j];
      }
    }
#pragma unroll
    for (int i = 0; i < 8; ++i)
#pragma unroll
      for (int j = 0; j < 8; ++j)
        c[i][j] += qa[i][0] * kb[j][0] + qa[i][1] * kb[j][1]
                 + qa[i][2] * kb[j][2] + qa[i][3] * kb[j][3];
  }
  float* srow = sbuf + ((size_t)blockIdx.z * 2048 + q0) * 4096 + s0;
  const u64* mrow = mbits + ((size_t)(b * 2048 + q0)) * 64 + (s0 >> 6);
#pragma unroll
  for (int i = 0; i < 8; ++i) {
    const int row = (ty << 3) + i;
    u64 wA = mrow[(size_t)row * 64];
    u64 wB = mrow[(size_t)row * 64 + 1];
    float4 o0, o1;
    o0.x = ((wA >> ((tx << 2) + 0)) & 1) ? c[i][0] * 0.125f : NEGV;
    o0.y = ((wA >> ((tx << 2) + 1)) & 1) ? c[i][1] * 0.125f : NEGV;
    o0.z = ((wA >> ((tx << 2) + 2)) & 1) ? c[i][2] * 0.125f : NEGV;
    o0.w = ((wA >> ((tx << 2) + 3)) & 1) ? c[i][3] * 0.125f : NEGV;
    o1.x = ((wB >> ((tx << 2) + 0)) & 1) ? c[i][4] * 0.125f : NEGV;
    o1.y = ((wB >> ((tx << 2) + 1)) & 1) ? c[i][5] * 0.125f : NEGV;
    o1.z = ((wB >> ((tx << 2) + 2)) & 1) ? c[i][6] * 0.125f : NEGV;
    o1.w = ((wB >> ((tx << 2) + 3)) & 1) ? c[i][7] * 0.125f : NEGV;
    *(float4*)&srow[(size_t)row * 4096 + (tx << 2)] = o0;
    *(float4*)&srow[(size_t)row * 4096 + 64 + (tx << 2)] = o1;
    // segment maxes (64-wide): reduce across the 16 tx lanes
    float m0 = fmaxf(fmaxf(o0.x, o0.y), fmaxf(o0.z, o0.w));
    float m1 = fmaxf(fmaxf(o1.x, o1.y), fmaxf(o1.z, o1.w));
#pragma unroll
    for (int off = 8; off; off >>= 1) {
      m0 = fmaxf(m0, __shfl_xor(m0, off, 64));
      m1 = fmaxf(m1, __shfl_xor(m1, off, 64));
    }
    if (tx == 0) {
      size_t sg = ((size_t)blockIdx.z * 2048 + q0 + row) * 64 + (s0 >> 6);
      segmax[sg] = m0;
      segmax[sg + 1] = m1;
    }
  }
}

// ---- fused top-k + softmax + ctx: one WAVE per q-row (4 waves/block).
// lo0/fm come from segmax (64 values/row, one per lane). Candidates >= lo0
// go to per-lane LDS slots (cap 16), read back to registers for the exact
// ord binary search; survivors -> LDS list (aliased onto candidate area);
// pipelined V-gather. ----
__global__ __launch_bounds__(256)
void topk_ctx_kernel(const float* __restrict__ sbuf, const float* __restrict__ segmax,
                     const float* __restrict__ vbuf, float* __restrict__ ctxbuf,
                     int sl0) {
  const int sl = sl0 + blockIdx.y;
  const int b = sl >> 3, h = sl & 7;
  const int w = threadIdx.x >> 6, lane = threadIdx.x & 63;
  const int qi = (blockIdx.x << 2) + w;
  __shared__ u64 cand_lds[4][NCAND][64];   // 32 KB/block
  u64* list = &cand_lds[w][0][0];          // reused after register readback
  const u64 lmask_lt = (1ull << lane) - 1ull;
  const u32 ordneg = f2ord(NEGV);

  const float* srow = sbuf + ((size_t)blockIdx.y * 2048 + qi) * 4096;

  // bounds from segment maxes: fm = row max, lo0 = min of 64 segment maxes
  float sm = segmax[((size_t)blockIdx.y * 2048 + qi) * 64 + lane];
  float fm = sm, lo0f = sm;
#pragma unroll
  for (int off = 32; off; off >>= 1) {
    fm = fmaxf(fm, __shfl_xor(fm, off, 64));
    lo0f = fminf(lo0f, __shfl_xor(lo0f, off, 64));
  }

  // stream the row once; per-lane candidates -> LDS (dynamic slot addressing)
  int cnt = 0;
#pragma unroll
  for (int jj = 0; jj < 16; jj += 4) {
    float4 v0 = *(const float4*)(srow + ((jj + 0) << 8) + (lane << 2));
    float4 v1 = *(const float4*)(srow + ((jj + 1) << 8) + (lane << 2));
    float4 v2 = *(const float4*)(srow + ((jj + 2) << 8) + (lane << 2));
    float4 v3 = *(const float4*)(srow + ((jj + 3) << 8) + (lane << 2));
    float xs[16] = {v0.x, v0.y, v0.z, v0.w, v1.x, v1.y, v1.z, v1.w,
                    v2.x, v2.y, v2.z, v2.w, v3.x, v3.y, v3.z, v3.w};
#pragma unroll
    for (int c = 0; c < 16; ++c) {
      float x = xs[c];
      if (x >= lo0f) {
        if (cnt < NCAND) {
          int sidx = ((jj + (c >> 2)) << 8) + (lane << 2) + (c & 3);
          cand_lds[w][cnt][lane] = ((u64)f2ord(x) << 32) | (u32)sidx;
        }
        cnt++;
      }
    }
  }
  const bool fb = (__ballot(cnt > NCAND) != 0ull);

  float esum = 0.f;
  int nsel = 0;
  bool meanpath = false;

  if (!fb) {
    u64 cv[NCAND];
#pragma unroll
    for (int j = 0; j < NCAND; ++j)
      cv[j] = (j < cnt) ? cand_lds[w][j][lane] : 0;
    // exact 64th-largest ord via binary search over candidates
    u32 lo = f2ord(lo0f), hi = f2ord(fm) + 1;
    while (hi - lo > 1) {
      u32 mid = lo + ((hi - lo) >> 1);
      u64 mp = (u64)mid << 32;
      int c = 0;
#pragma unroll
      for (int j = 0; j < NCAND; ++j)
        c += __popcll(__ballot(cv[j] >= mp));
      if (c >= 64) lo = mid; else hi = mid;
    }
    const u64 tp = (u64)lo << 32;
    // survivors -> list (ballot-prefix), exp + esum
    int base = 0;
#pragma unroll
    for (int j = 0; j < NCAND; ++j) {
      bool pred = cv[j] >= tp;
      u64 m = __ballot(pred);
      int ofs = base + __popcll(m & lmask_lt);
      if (pred && ofs < LISTCAP) {
        float ev = __expf(ord2f((u32)(cv[j] >> 32)) - fm);
        list[ofs] = ((u64)((u32)cv[j]) << 32) | (u64)__float_as_uint(ev);
        esum += ev;
      }
      base += (int)__popcll(m);
    }
    nsel = base < LISTCAP ? base : LISTCAP;
  } else {
    // rare exact fallback: full binary search streaming the row (L2-hot)
    u32 lo = f2ord(lo0f), hi = f2ord(fm) + 1;
    while (hi - lo > 1) {
      u32 mid = lo + ((hi - lo) >> 1);
      float midf = ord2f(mid);
      int c = 0;
      for (int j = 0; j < 16; ++j) {
        float4 v = *(const float4*)(srow + (j << 8) + (lane << 2));
        c += __popcll(__ballot(v.x >= midf)) + __popcll(__ballot(v.y >= midf)) +
             __popcll(__ballot(v.z >= midf)) + __popcll(__ballot(v.w >= midf));
      }
      if (c >= 64) lo = mid; else hi = mid;
    }
    const float thrf = ord2f(lo);
    int base = 0;
    for (int j = 0; j < 16; ++j) {
      float4 v = *(const float4*)(srow + (j << 8) + (lane << 2));
      float xs[4] = {v.x, v.y, v.z, v.w};
#pragma unroll
      for (int cpos = 0; cpos < 4; ++cpos) {
        float x = xs[cpos];
        bool pred = (x >= thrf) && (x != NEGV);
        u64 m = __ballot(pred);
        int ofs = base + __popcll(m & lmask_lt);
        if (pred && ofs < LISTCAP) {
          int sidx = (j << 8) + (lane << 2) + cpos;
          float ev = __expf(x - fm);
          list[ofs] = ((u64)(u32)sidx << 32) | (u64)__float_as_uint(ev);
          esum += ev;
        }
        base += (int)__popcll(m);
      }
    }
    nsel = base < LISTCAP ? base : LISTCAP;
    if (base == 0) meanpath = true;  // fully masked row
  }

#pragma unroll
  for (int off = 32; off; off >>= 1) esum += __shfl_xor(esum, off, 64);
  const float* vb = vbuf + h * 64 + lane;
  float outv;
  if (!meanpath) {
    const float rs = 1.0f / esum;
    int pad = (8 - (nsel & 7)) & 7;
    if (lane < pad && nsel + lane < LISTCAP) list[nsel + lane] = 0;  // ev=+0, idx=0
    int n8 = nsel + pad;
    if (n8 > LISTCAP) n8 = LISTCAP;
    float a0 = 0.f, a1 = 0.f, a2 = 0.f, a3 = 0.f;
    float a4 = 0.f, a5 = 0.f, a6 = 0.f, a7 = 0.f;
    for (int g = 0; g < n8; g += 8) {
      u64 p0 = list[g + 0], p1 = list[g + 1], p2 = list[g + 2], p3 = list[g + 3];
      u64 p4 = list[g + 4], p5 = list[g + 5], p6 = list[g + 6], p7 = list[g + 7];
      a0 += __uint_as_float((u32)p0) * vb[(size_t)(p0 >> 32) * 512];
      a1 += __uint_as_float((u32)p1) * vb[(size_t)(p1 >> 32) * 512];
      a2 += __uint_as_float((u32)p2) * vb[(size_t)(p2 >> 32) * 512];
      a3 += __uint_as_float((u32)p3) * vb[(size_t)(p3 >> 32) * 512];
      a4 += __uint_as_float((u32)p4) * vb[(size_t)(p4 >> 32) * 512];
      a5 += __uint_as_float((u32)p5) * vb[(size_t)(p5 >> 32) * 512];
      a6 += __uint_as_float((u32)p6) * vb[(size_t)(p6 >> 32) * 512];
      a7 += __uint_as_float((u32)p7) * vb[(size_t)(p7 >> 32) * 512];
    }
    outv = (((a0 + a1) + (a2 + a3)) + ((a4 + a5) + (a6 + a7))) * rs;
  } else {
    float acc = 0.f;
    for (int s = 0; s < 4096; ++s) acc += vb[(size_t)s * 512];
    outv = acc * (1.0f / 4096.0f);
  }
  ctxbuf[((size_t)(b * 2048 + qi)) * 512 + h * 64 + lane] = outv;
}

extern "C" void kernel_launch(void* const* d_in, const int* in_sizes, int n_in,
                              void* d_out, int out_size, void* d_ws, size_t ws_size,
                              hipStream_t stream) {
  const float* main_in = (const float*)d_in[0];
  const float* side_in = (const float*)d_in[1];
  const int*   mask    = (const int*)d_in[2];
  const float* Wq = (const float*)d_in[3];
  const float* bq = (const float*)d_in[4];
  const float* Wk = (const float*)d_in[5];
  const float* bk = (const float*)d_in[6];
  const float* Wv = (const float*)d_in[7];
  const float* bv = (const float*)d_in[8];
  const float* Wo = (const float*)d_in[9];
  const float* bo = (const float*)d_in[10];
  float* out = (float*)d_out;

  char* ws = (char*)d_ws;
  float* qT   = (float*)(ws);                       // 8 MB
  float* kT   = (float*)(ws + ((size_t)8 << 20));   // 8 MB
  float* vbuf = (float*)(ws + ((size_t)16 << 20));  // 8 MB
  float* ctxb = (float*)(ws + ((size_t)24 << 20));  // 8 MB
  u64* mbits  = (u64*)(ws + ((size_t)32 << 20));    // 2 MB
  const size_t base = (size_t)34 << 20;
  const size_t sliceb = (size_t)2048 * 4096 * 4;    // 32 MB scores/slice
  const size_t segb   = (size_t)2048 * 64 * 4;      // 512 KB segmax/slice
  const size_t per = sliceb + segb;

  int nz = 1;
  if (ws_size > base + per) {
    size_t m = (ws_size - base) / per;
    nz = (int)(m > 16 ? 16 : m);
  }
  float* sbuf = (float*)(ws + base);
  float* smax = (float*)(ws + base + (size_t)nz * sliceb);

  pack_mask<<<1024, 256, 0, stream>>>(mask, mbits);
  gemm_bias_T<<<dim3(8, 64), 256, 0, stream>>>(main_in, Wq, bq, qT, 11);
  gemm_bias_T<<<dim3(8, 64), 256, 0, stream>>>(side_in, Wk, bk, kT, 12);
  gemm_bias  <<<dim3(8, 64), 256, 0, stream>>>(side_in, Wv, bv, vbuf);

  for (int sl0 = 0; sl0 < 16; sl0 += nz) {
    int z = nz < (16 - sl0) ? nz : (16 - sl0);
    score_kernel   <<<dim3(32, 16, z), 256, 0, stream>>>(qT, kT, mbits, sbuf, smax, sl0);
    topk_ctx_kernel<<<dim3(512, z), 256, 0, stream>>>(sbuf, smax, vbuf, ctxb, sl0);
  }

  gemm_bias<<<dim3(8, 64), 256, 0, stream>>>(ctxb, Wo, bo, out);
}

// Round 8
// 754.078 us; speedup vs baseline: 2.9728x; 1.0869x over previous
//
#include <hip/hip_runtime.h>
#include <stdint.h>

typedef uint32_t u32;
typedef unsigned long long u64;

#define NEGV (-1e9f)
#define NCAND 16
#define LISTCAP 256

__device__ __forceinline__ u32 f2ord(float f) {
  u32 x = __float_as_uint(f);
  return (x & 0x80000000u) ? ~x : (x | 0x80000000u);
}
__device__ __forceinline__ float ord2f(u32 u) {
  u32 x = (u & 0x80000000u) ? (u ^ 0x80000000u) : ~u;
  return __uint_as_float(x);
}

// ---- mask packer: int32 mask [2][2048][4096] -> u64 bits [2][2048][64] ----
__global__ __launch_bounds__(256)
void pack_mask(const int* __restrict__ mask, u64* __restrict__ mbits) {
  int w = blockIdx.x * 256 + threadIdx.x;
  const int4* p = (const int4*)(mask + (size_t)w * 64);
  u64 bits = 0;
#pragma unroll
  for (int j = 0; j < 16; ++j) {
    int4 m = p[j];
    if (m.x) bits |= 1ull << (j * 4 + 0);
    if (m.y) bits |= 1ull << (j * 4 + 1);
    if (m.z) bits |= 1ull << (j * 4 + 2);
    if (m.w) bits |= 1ull << (j * 4 + 3);
  }
  mbits[w] = bits;
}

// ---- C[M x 512] = A[M x 512] @ W[512 x 512] + bias (row-major out) ----
__global__ __launch_bounds__(256)
void gemm_bias(const float* __restrict__ A, const float* __restrict__ W,
               const float* __restrict__ bias, float* __restrict__ C) {
  __shared__ float As[16][68];
  __shared__ float Bs[16][64];
  const int tid = threadIdx.x;
  const int tx = tid & 15, ty = tid >> 4;
  const int n0 = blockIdx.x << 6, m0 = blockIdx.y << 6;
  float c[4][4] = {};
  for (int k0 = 0; k0 < 512; k0 += 16) {
    {
      const int row = tid >> 2, kp = (tid & 3) << 2;
      float4 av = *(const float4*)&A[(size_t)(m0 + row) * 512 + k0 + kp];
      As[kp + 0][row] = av.x;
      As[kp + 1][row] = av.y;
      As[kp + 2][row] = av.z;
      As[kp + 3][row] = av.w;
      const int kk = tid >> 4, np = (tid & 15) << 2;
      *(float4*)&Bs[kk][np] = *(const float4*)&W[(size_t)(k0 + kk) * 512 + n0 + np];
    }
    __syncthreads();
#pragma unroll
    for (int kk = 0; kk < 16; ++kk) {
      float4 a = *(const float4*)&As[kk][ty << 2];
      float4 b = *(const float4*)&Bs[kk][tx << 2];
      c[0][0] += a.x * b.x; c[0][1] += a.x * b.y; c[0][2] += a.x * b.z; c[0][3] += a.x * b.w;
      c[1][0] += a.y * b.x; c[1][1] += a.y * b.y; c[1][2] += a.y * b.z; c[1][3] += a.y * b.w;
      c[2][0] += a.z * b.x; c[2][1] += a.z * b.y; c[2][2] += a.z * b.z; c[2][3] += a.z * b.w;
      c[3][0] += a.w * b.x; c[3][1] += a.w * b.y; c[3][2] += a.w * b.z; c[3][3] += a.w * b.w;
    }
    __syncthreads();
  }
  float4 bv = *(const float4*)&bias[n0 + (tx << 2)];
#pragma unroll
  for (int i = 0; i < 4; ++i) {
    float4 o;
    o.x = c[i][0] + bv.x; o.y = c[i][1] + bv.y;
    o.z = c[i][2] + bv.z; o.w = c[i][3] + bv.w;
    *(float4*)&C[(size_t)(m0 + (ty << 2) + i) * 512 + n0 + (tx << 2)] = o;
  }
}

// ---- same GEMM math, but stores k-major transposed ----
__global__ __launch_bounds__(256)
void gemm_bias_T(const float* __restrict__ A, const float* __restrict__ W,
                 const float* __restrict__ bias, float* __restrict__ CT, int qsh) {
  __shared__ float As[16][68];
  __shared__ float Bs[16][64];
  const int tid = threadIdx.x;
  const int tx = tid & 15, ty = tid >> 4;
  const int n0 = blockIdx.x << 6, m0 = blockIdx.y << 6;
  float c[4][4] = {};
  for (int k0 = 0; k0 < 512; k0 += 16) {
    {
      const int row = tid >> 2, kp = (tid & 3) << 2;
      float4 av = *(const float4*)&A[(size_t)(m0 + row) * 512 + k0 + kp];
      As[kp + 0][row] = av.x;
      As[kp + 1][row] = av.y;
      As[kp + 2][row] = av.z;
      As[kp + 3][row] = av.w;
      const int kk = tid >> 4, np = (tid & 15) << 2;
      *(float4*)&Bs[kk][np] = *(const float4*)&W[(size_t)(k0 + kk) * 512 + n0 + np];
    }
    __syncthreads();
#pragma unroll
    for (int kk = 0; kk < 16; ++kk) {
      float4 a = *(const float4*)&As[kk][ty << 2];
      float4 b = *(const float4*)&Bs[kk][tx << 2];
      c[0][0] += a.x * b.x; c[0][1] += a.x * b.y; c[0][2] += a.x * b.z; c[0][3] += a.x * b.w;
      c[1][0] += a.y * b.x; c[1][1] += a.y * b.y; c[1][2] += a.y * b.z; c[1][3] += a.y * b.w;
      c[2][0] += a.z * b.x; c[2][1] += a.z * b.y; c[2][2] += a.z * b.z; c[2][3] += a.z * b.w;
      c[3][0] += a.w * b.x; c[3][1] += a.w * b.y; c[3][2] += a.w * b.z; c[3][3] += a.w * b.w;
    }
    __syncthreads();
  }
  float4 bv = *(const float4*)&bias[n0 + (tx << 2)];
  float bvv[4] = {bv.x, bv.y, bv.z, bv.w};
  const int qlen = 1 << qsh;
  const int qmask = qlen - 1;
#pragma unroll
  for (int i = 0; i < 4; ++i) {
#pragma unroll
    for (int j = 0; j < 4; ++j) {
      float val = c[i][j] + bvv[j];
      int m = m0 + (ty << 2) + i;
      int n = n0 + (tx << 2) + j;
      int h = n >> 6, d = n & 63;
      int bb = m >> qsh, q = m & qmask;
      CT[(((size_t)bb * 8 + h) * 64 + d) * qlen + q] = val;
    }
  }
}

// ---- scores: 128(q) x 128(s) tile per block, 8x8 micro, BK=32 two-stage
// staging (LDS 32 KB -> ~5 blocks/CU). K-order and FMA statement shape are
// identical to the 64-k version => scores bit-identical.
// Emits per-row 32-wide segment maxes of the MASKED scores (128/row). ----
__global__ __launch_bounds__(256)
void score_kernel(const float* __restrict__ qT, const float* __restrict__ kT,
                  const u64* __restrict__ mbits, float* __restrict__ sbuf,
                  float* __restrict__ segmax, int sl0) {
  __shared__ float Qs[32][128];
  __shared__ float Ks[32][128];
  const int sl = sl0 + blockIdx.z;
  const int b = sl >> 3, h = sl & 7;
  const int s0 = blockIdx.x << 7, q0 = blockIdx.y << 7;
  const int tid = threadIdx.x;
  const float* qbase = qT + (size_t)sl * 64 * 2048 + q0;
  const float* kbase = kT + (size_t)h * 64 * 4096 + s0;
  const int tx = tid & 15, ty = tid >> 4;
  float4* Qf = (float4*)&Qs[0][0];
  float4* Kf = (float4*)&Ks[0][0];
  float c[8][8] = {};
  for (int half = 0; half < 2; ++half) {
#pragma unroll
    for (int u = 0; u < 4; ++u) {
      int i = (u << 8) + tid;              // f4 index 0..1023
      int row = i >> 5, col = (i & 31) << 2;
      Qf[i] = *(const float4*)(qbase + (size_t)(half * 32 + row) * 2048 + col);
      Kf[i] = *(const float4*)(kbase + (size_t)(half * 32 + row) * 4096 + col);
    }
    __syncthreads();
#pragma unroll 4
    for (int g = 0; g < 8; ++g) {
      const int kk = g << 2;
      float qa[8][4], kb[8][4];
#pragma unroll
      for (int t = 0; t < 4; ++t) {
#pragma unroll
        for (int i = 0; i < 8; ++i) qa[i][t] = Qs[kk + t][(ty << 3) + i];
#pragma unroll
        for (int j = 0; j < 4; ++j) {
          kb[j][t]     = Ks[kk + t][(tx << 2) + j];
          kb[4 + j][t] = Ks[kk + t][64 + (tx << 2) + j];
        }
      }
#pragma unroll
      for (int i = 0; i < 8; ++i)
#pragma unroll
        for (int j = 0; j < 8; ++j)
          c[i][j] += qa[i][0] * kb[j][0] + qa[i][1] * kb[j][1]
                   + qa[i][2] * kb[j][2] + qa[i][3] * kb[j][3];
    }
    __syncthreads();
  }
  float* srow = sbuf + ((size_t)blockIdx.z * 2048 + q0) * 4096 + s0;
  const u64* mrow = mbits + ((size_t)(b * 2048 + q0)) * 64 + (s0 >> 6);
#pragma unroll
  for (int i = 0; i < 8; ++i) {
    const int row = (ty << 3) + i;
    u64 wA = mrow[(size_t)row * 64];
    u64 wB = mrow[(size_t)row * 64 + 1];
    float4 o0, o1;
    o0.x = ((wA >> ((tx << 2) + 0)) & 1) ? c[i][0] * 0.125f : NEGV;
    o0.y = ((wA >> ((tx << 2) + 1)) & 1) ? c[i][1] * 0.125f : NEGV;
    o0.z = ((wA >> ((tx << 2) + 2)) & 1) ? c[i][2] * 0.125f : NEGV;
    o0.w = ((wA >> ((tx << 2) + 3)) & 1) ? c[i][3] * 0.125f : NEGV;
    o1.x = ((wB >> ((tx << 2) + 0)) & 1) ? c[i][4] * 0.125f : NEGV;
    o1.y = ((wB >> ((tx << 2) + 1)) & 1) ? c[i][5] * 0.125f : NEGV;
    o1.z = ((wB >> ((tx << 2) + 2)) & 1) ? c[i][6] * 0.125f : NEGV;
    o1.w = ((wB >> ((tx << 2) + 3)) & 1) ? c[i][7] * 0.125f : NEGV;
    *(float4*)&srow[(size_t)row * 4096 + (tx << 2)] = o0;
    *(float4*)&srow[(size_t)row * 4096 + 64 + (tx << 2)] = o1;
    // 32-wide segment maxes: tx<8 covers s-local [0,32)/[64,96); tx>=8 the others
    float m0 = fmaxf(fmaxf(o0.x, o0.y), fmaxf(o0.z, o0.w));
    float m1 = fmaxf(fmaxf(o1.x, o1.y), fmaxf(o1.z, o1.w));
#pragma unroll
    for (int off = 4; off; off >>= 1) {
      m0 = fmaxf(m0, __shfl_xor(m0, off, 64));
      m1 = fmaxf(m1, __shfl_xor(m1, off, 64));
    }
    if ((tx & 7) == 0) {
      size_t sg = ((size_t)blockIdx.z * 2048 + q0 + row) * 128 + (s0 >> 5) + (tx >> 3);
      segmax[sg] = m0;
      segmax[sg + 2] = m1;
    }
  }
}

// ---- fused top-k + softmax + ctx: one WAVE per q-row (4 waves/block).
// T = 64th-largest of the 128 segmaxes (provable lower bound on the 64th-
// largest element). Lanes load their two contiguous 32-float segments only
// if segmax >= T; candidates = x >= T; exact ord binary search; survivors
// -> LDS list; pipelined V-gather. ----
__global__ __launch_bounds__(256)
void topk_ctx_kernel(const float* __restrict__ sbuf, const float* __restrict__ segmax,
                     const float* __restrict__ vbuf, float* __restrict__ ctxbuf,
                     int sl0) {
  const int sl = sl0 + blockIdx.y;
  const int b = sl >> 3, h = sl & 7;
  const int w = threadIdx.x >> 6, lane = threadIdx.x & 63;
  const int qi = (blockIdx.x << 2) + w;
  __shared__ u64 cand_lds[4][NCAND][64];   // 32 KB/block
  u64* list = &cand_lds[w][0][0];
  const u64 lmask_lt = (1ull << lane) - 1ull;
  const u32 ordneg = f2ord(NEGV);

  const float* srow = sbuf + ((size_t)blockIdx.y * 2048 + qi) * 4096;

  // segment maxes: 2 per lane (lane's own contiguous 64-elem region)
  float2 smv = *(const float2*)(segmax + ((size_t)blockIdx.y * 2048 + qi) * 128 + (lane << 1));
  u32 so0 = f2ord(smv.x), so1 = f2ord(smv.y);
  u32 mxo = so0 > so1 ? so0 : so1;
  u32 mno = so0 < so1 ? so0 : so1;
#pragma unroll
  for (int off = 32; off; off >>= 1) {
    u32 a = (u32)__shfl_xor((int)mxo, off, 64);
    u32 c = (u32)__shfl_xor((int)mno, off, 64);
    mxo = a > mxo ? a : mxo;
    mno = c < mno ? c : mno;
  }
  const float fm = ord2f(mxo);
  // T = largest v with count(segmax >= v) >= 64
  {
    u32 lo = mno, hi = mxo + 1;
    while (hi - lo > 1) {
      u32 mid = lo + ((hi - lo) >> 1);
      int c = __popcll(__ballot(so0 >= mid)) + __popcll(__ballot(so1 >= mid));
      if (c >= 64) lo = mid; else hi = mid;
    }
    mno = lo;  // reuse as ordT
  }
  const u32 ordT = mno;
  const float Tf = ord2f(ordT);

  // load only segments with segmax >= T; collect candidates x >= T
  int cnt = 0;
  const float* lbase = srow + (lane << 6);
#pragma unroll
  for (int reg = 0; reg < 2; ++reg) {
    bool active = (reg == 0) ? (smv.x >= Tf) : (smv.y >= Tf);
    if (active) {
      const float* rb = lbase + (reg << 5);
      float4 v0 = *(const float4*)(rb + 0);
      float4 v1 = *(const float4*)(rb + 4);
      float4 v2 = *(const float4*)(rb + 8);
      float4 v3 = *(const float4*)(rb + 12);
      float4 v4 = *(const float4*)(rb + 16);
      float4 v5 = *(const float4*)(rb + 20);
      float4 v6 = *(const float4*)(rb + 24);
      float4 v7 = *(const float4*)(rb + 28);
      float xs[32] = {v0.x, v0.y, v0.z, v0.w, v1.x, v1.y, v1.z, v1.w,
                      v2.x, v2.y, v2.z, v2.w, v3.x, v3.y, v3.z, v3.w,
                      v4.x, v4.y, v4.z, v4.w, v5.x, v5.y, v5.z, v5.w,
                      v6.x, v6.y, v6.z, v6.w, v7.x, v7.y, v7.z, v7.w};
#pragma unroll
      for (int cc = 0; cc < 32; ++cc) {
        if (xs[cc] >= Tf) {
          if (cnt < NCAND) {
            int sidx = (lane << 6) + (reg << 5) + cc;
            cand_lds[w][cnt][lane] = ((u64)f2ord(xs[cc]) << 32) | (u32)sidx;
          }
          cnt++;
        }
      }
    }
  }
  const bool fb = (__ballot(cnt > NCAND) != 0ull);

  float esum = 0.f;
  int nsel = 0;
  bool meanpath = false;

  if (!fb) {
    u64 cv[NCAND];
#pragma unroll
    for (int j = 0; j < NCAND; ++j)
      cv[j] = (j < cnt) ? cand_lds[w][j][lane] : 0;
    // exact 64th-largest ord via binary search over candidates
    u32 lo = ordT, hi = mxo + 1;
    while (hi - lo > 1) {
      u32 mid = lo + ((hi - lo) >> 1);
      u64 mp = (u64)mid << 32;
      int c = 0;
#pragma unroll
      for (int j = 0; j < NCAND; ++j)
        c += __popcll(__ballot(cv[j] >= mp));
      if (c >= 64) lo = mid; else hi = mid;
    }
    const u64 tp = (u64)lo << 32;
    int base = 0;
#pragma unroll
    for (int j = 0; j < NCAND; ++j) {
      bool pred = cv[j] >= tp;
      u64 m = __ballot(pred);
      int ofs = base + __popcll(m & lmask_lt);
      if (pred && ofs < LISTCAP) {
        float ev = __expf(ord2f((u32)(cv[j] >> 32)) - fm);
        list[ofs] = ((u64)((u32)cv[j]) << 32) | (u64)__float_as_uint(ev);
        esum += ev;
      }
      base += (int)__popcll(m);
    }
    nsel = base < LISTCAP ? base : LISTCAP;
  } else {
    // rare exact fallback: full binary search streaming the row (L2/L3-hot)
    u32 lo = ordT, hi = mxo + 1;
    while (hi - lo > 1) {
      u32 mid = lo + ((hi - lo) >> 1);
      float midf = ord2f(mid);
      int c = 0;
      for (int j = 0; j < 16; ++j) {
        float4 v = *(const float4*)(srow + (j << 8) + (lane << 2));
        c += __popcll(__ballot(v.x >= midf)) + __popcll(__ballot(v.y >= midf)) +
             __popcll(__ballot(v.z >= midf)) + __popcll(__ballot(v.w >= midf));
      }
      if (c >= 64) lo = mid; else hi = mid;
    }
    const float thrf = ord2f(lo);
    int base = 0;
    for (int j = 0; j < 16; ++j) {
      float4 v = *(const float4*)(srow + (j << 8) + (lane << 2));
      float xs[4] = {v.x, v.y, v.z, v.w};
#pragma unroll
      for (int cpos = 0; cpos < 4; ++cpos) {
        float x = xs[cpos];
        bool pred = (x >= thrf) && (x != NEGV);
        u64 m = __ballot(pred);
        int ofs = base + __popcll(m & lmask_lt);
        if (pred && ofs < LISTCAP) {
          int sidx = (j << 8) + (lane << 2) + cpos;
          float ev = __expf(x - fm);
          list[ofs] = ((u64)(u32)sidx << 32) | (u64)__float_as_uint(ev);
          esum += ev;
        }
        base += (int)__popcll(m);
      }
    }
    nsel = base < LISTCAP ? base : LISTCAP;
    if (base == 0) meanpath = true;  // fully masked row
  }

#pragma unroll
  for (int off = 32; off; off >>= 1) esum += __shfl_xor(esum, off, 64);
  const float* vb = vbuf + h * 64 + lane;
  float outv;
  if (!meanpath) {
    const float rs = 1.0f / esum;
    int pad = (8 - (nsel & 7)) & 7;
    if (lane < pad && nsel + lane < LISTCAP) list[nsel + lane] = 0;  // ev=+0, idx=0
    int n8 = nsel + pad;
    if (n8 > LISTCAP) n8 = LISTCAP;
    float a0 = 0.f, a1 = 0.f, a2 = 0.f, a3 = 0.f;
    float a4 = 0.f, a5 = 0.f, a6 = 0.f, a7 = 0.f;
    for (int g = 0; g < n8; g += 8) {
      u64 p0 = list[g + 0], p1 = list[g + 1], p2 = list[g + 2], p3 = list[g + 3];
      u64 p4 = list[g + 4], p5 = list[g + 5], p6 = list[g + 6], p7 = list[g + 7];
      a0 += __uint_as_float((u32)p0) * vb[(size_t)(p0 >> 32) * 512];
      a1 += __uint_as_float((u32)p1) * vb[(size_t)(p1 >> 32) * 512];
      a2 += __uint_as_float((u32)p2) * vb[(size_t)(p2 >> 32) * 512];
      a3 += __uint_as_float((u32)p3) * vb[(size_t)(p3 >> 32) * 512];
      a4 += __uint_as_float((u32)p4) * vb[(size_t)(p4 >> 32) * 512];
      a5 += __uint_as_float((u32)p5) * vb[(size_t)(p5 >> 32) * 512];
      a6 += __uint_as_float((u32)p6) * vb[(size_t)(p6 >> 32) * 512];
      a7 += __uint_as_float((u32)p7) * vb[(size_t)(p7 >> 32) * 512];
    }
    outv = (((a0 + a1) + (a2 + a3)) + ((a4 + a5) + (a6 + a7))) * rs;
  } else {
    float acc = 0.f;
    for (int s = 0; s < 4096; ++s) acc += vb[(size_t)s * 512];
    outv = acc * (1.0f / 4096.0f);
  }
  ctxbuf[((size_t)(b * 2048 + qi)) * 512 + h * 64 + lane] = outv;
}

extern "C" void kernel_launch(void* const* d_in, const int* in_sizes, int n_in,
                              void* d_out, int out_size, void* d_ws, size_t ws_size,
                              hipStream_t stream) {
  const float* main_in = (const float*)d_in[0];
  const float* side_in = (const float*)d_in[1];
  const int*   mask    = (const int*)d_in[2];
  const float* Wq = (const float*)d_in[3];
  const float* bq = (const float*)d_in[4];
  const float* Wk = (const float*)d_in[5];
  const float* bk = (const float*)d_in[6];
  const float* Wv = (const float*)d_in[7];
  const float* bv = (const float*)d_in[8];
  const float* Wo = (const float*)d_in[9];
  const float* bo = (const float*)d_in[10];
  float* out = (float*)d_out;

  char* ws = (char*)d_ws;
  float* qT   = (float*)(ws);                       // 8 MB
  float* kT   = (float*)(ws + ((size_t)8 << 20));   // 8 MB
  float* vbuf = (float*)(ws + ((size_t)16 << 20));  // 8 MB
  float* ctxb = (float*)(ws + ((size_t)24 << 20));  // 8 MB
  u64* mbits  = (u64*)(ws + ((size_t)32 << 20));    // 2 MB
  const size_t base = (size_t)34 << 20;
  const size_t sliceb = (size_t)2048 * 4096 * 4;    // 32 MB scores/slice
  const size_t segb   = (size_t)2048 * 128 * 4;     // 1 MB segmax/slice
  const size_t per = sliceb + segb;

  // cap nz at 4 so the slice working set (~132 MB) stays L3-resident
  int nz = 1;
  if (ws_size > base + per) {
    size_t m = (ws_size - base) / per;
    nz = (int)(m > 4 ? 4 : m);
  }
  float* sbuf = (float*)(ws + base);
  float* smax = (float*)(ws + base + (size_t)nz * sliceb);

  pack_mask<<<1024, 256, 0, stream>>>(mask, mbits);
  gemm_bias_T<<<dim3(8, 64), 256, 0, stream>>>(main_in, Wq, bq, qT, 11);
  gemm_bias_T<<<dim3(8, 64), 256, 0, stream>>>(side_in, Wk, bk, kT, 12);
  gemm_bias  <<<dim3(8, 64), 256, 0, stream>>>(side_in, Wv, bv, vbuf);

  for (int sl0 = 0; sl0 < 16; sl0 += nz) {
    int z = nz < (16 - sl0) ? nz : (16 - sl0);
    score_kernel   <<<dim3(32, 16, z), 256, 0, stream>>>(qT, kT, mbits, sbuf, smax, sl0);
    topk_ctx_kernel<<<dim3(512, z), 256, 0, stream>>>(sbuf, smax, vbuf, ctxb, sl0);
  }

  gemm_bias<<<dim3(8, 64), 256, 0, stream>>>(ctxb, Wo, bo, out);
}

// Round 9
// 752.063 us; speedup vs baseline: 2.9808x; 1.0027x over previous
//
#include <hip/hip_runtime.h>
#include <stdint.h>

typedef uint32_t u32;
typedef unsigned long long u64;

#define NEGV (-1e9f)
#define NCAND 16
#define LISTCAP 256

__device__ __forceinline__ u32 f2ord(float f) {
  u32 x = __float_as_uint(f);
  return (x & 0x80000000u) ? ~x : (x | 0x80000000u);
}
__device__ __forceinline__ float ord2f(u32 u) {
  u32 x = (u & 0x80000000u) ? (u ^ 0x80000000u) : ~u;
  return __uint_as_float(x);
}

// ---- mask packer: int32 mask [2][2048][4096] -> u64 bits [2][2048][64] ----
__global__ __launch_bounds__(256)
void pack_mask(const int* __restrict__ mask, u64* __restrict__ mbits) {
  int w = blockIdx.x * 256 + threadIdx.x;
  const int4* p = (const int4*)(mask + (size_t)w * 64);
  u64 bits = 0;
#pragma unroll
  for (int j = 0; j < 16; ++j) {
    int4 m = p[j];
    if (m.x) bits |= 1ull << (j * 4 + 0);
    if (m.y) bits |= 1ull << (j * 4 + 1);
    if (m.z) bits |= 1ull << (j * 4 + 2);
    if (m.w) bits |= 1ull << (j * 4 + 3);
  }
  mbits[w] = bits;
}

// ---- C[M x 512] = A[M x 512] @ W[512 x 512] + bias (row-major out) ----
__global__ __launch_bounds__(256)
void gemm_bias(const float* __restrict__ A, const float* __restrict__ W,
               const float* __restrict__ bias, float* __restrict__ C) {
  __shared__ float As[16][68];
  __shared__ float Bs[16][64];
  const int tid = threadIdx.x;
  const int tx = tid & 15, ty = tid >> 4;
  const int n0 = blockIdx.x << 6, m0 = blockIdx.y << 6;
  float c[4][4] = {};
  for (int k0 = 0; k0 < 512; k0 += 16) {
    {
      const int row = tid >> 2, kp = (tid & 3) << 2;
      float4 av = *(const float4*)&A[(size_t)(m0 + row) * 512 + k0 + kp];
      As[kp + 0][row] = av.x;
      As[kp + 1][row] = av.y;
      As[kp + 2][row] = av.z;
      As[kp + 3][row] = av.w;
      const int kk = tid >> 4, np = (tid & 15) << 2;
      *(float4*)&Bs[kk][np] = *(const float4*)&W[(size_t)(k0 + kk) * 512 + n0 + np];
    }
    __syncthreads();
#pragma unroll
    for (int kk = 0; kk < 16; ++kk) {
      float4 a = *(const float4*)&As[kk][ty << 2];
      float4 b = *(const float4*)&Bs[kk][tx << 2];
      c[0][0] += a.x * b.x; c[0][1] += a.x * b.y; c[0][2] += a.x * b.z; c[0][3] += a.x * b.w;
      c[1][0] += a.y * b.x; c[1][1] += a.y * b.y; c[1][2] += a.y * b.z; c[1][3] += a.y * b.w;
      c[2][0] += a.z * b.x; c[2][1] += a.z * b.y; c[2][2] += a.z * b.z; c[2][3] += a.z * b.w;
      c[3][0] += a.w * b.x; c[3][1] += a.w * b.y; c[3][2] += a.w * b.z; c[3][3] += a.w * b.w;
    }
    __syncthreads();
  }
  float4 bv = *(const float4*)&bias[n0 + (tx << 2)];
#pragma unroll
  for (int i = 0; i < 4; ++i) {
    float4 o;
    o.x = c[i][0] + bv.x; o.y = c[i][1] + bv.y;
    o.z = c[i][2] + bv.z; o.w = c[i][3] + bv.w;
    *(float4*)&C[(size_t)(m0 + (ty << 2) + i) * 512 + n0 + (tx << 2)] = o;
  }
}

// ---- same GEMM math, but stores k-major transposed ----
__global__ __launch_bounds__(256)
void gemm_bias_T(const float* __restrict__ A, const float* __restrict__ W,
                 const float* __restrict__ bias, float* __restrict__ CT, int qsh) {
  __shared__ float As[16][68];
  __shared__ float Bs[16][64];
  const int tid = threadIdx.x;
  const int tx = tid & 15, ty = tid >> 4;
  const int n0 = blockIdx.x << 6, m0 = blockIdx.y << 6;
  float c[4][4] = {};
  for (int k0 = 0; k0 < 512; k0 += 16) {
    {
      const int row = tid >> 2, kp = (tid & 3) << 2;
      float4 av = *(const float4*)&A[(size_t)(m0 + row) * 512 + k0 + kp];
      As[kp + 0][row] = av.x;
      As[kp + 1][row] = av.y;
      As[kp + 2][row] = av.z;
      As[kp + 3][row] = av.w;
      const int kk = tid >> 4, np = (tid & 15) << 2;
      *(float4*)&Bs[kk][np] = *(const float4*)&W[(size_t)(k0 + kk) * 512 + n0 + np];
    }
    __syncthreads();
#pragma unroll
    for (int kk = 0; kk < 16; ++kk) {
      float4 a = *(const float4*)&As[kk][ty << 2];
      float4 b = *(const float4*)&Bs[kk][tx << 2];
      c[0][0] += a.x * b.x; c[0][1] += a.x * b.y; c[0][2] += a.x * b.z; c[0][3] += a.x * b.w;
      c[1][0] += a.y * b.x; c[1][1] += a.y * b.y; c[1][2] += a.y * b.z; c[1][3] += a.y * b.w;
      c[2][0] += a.z * b.x; c[2][1] += a.z * b.y; c[2][2] += a.z * b.z; c[2][3] += a.z * b.w;
      c[3][0] += a.w * b.x; c[3][1] += a.w * b.y; c[3][2] += a.w * b.z; c[3][3] += a.w * b.w;
    }
    __syncthreads();
  }
  float4 bv = *(const float4*)&bias[n0 + (tx << 2)];
  float bvv[4] = {bv.x, bv.y, bv.z, bv.w};
  const int qlen = 1 << qsh;
  const int qmask = qlen - 1;
#pragma unroll
  for (int i = 0; i < 4; ++i) {
#pragma unroll
    for (int j = 0; j < 4; ++j) {
      float val = c[i][j] + bvv[j];
      int m = m0 + (ty << 2) + i;
      int n = n0 + (tx << 2) + j;
      int h = n >> 6, d = n & 63;
      int bb = m >> qsh, q = m & qmask;
      CT[(((size_t)bb * 8 + h) * 64 + d) * qlen + q] = val;
    }
  }
}

// ---- scores: 128(q) x 128(s) tile per block, 8x8 micro, BK=64 single-stage
// staging (empirically faster than BK=32 two-stage). Emits per-row 32-wide
// segment maxes of the MASKED scores (128/row). Scores bit-identical across
// stagings (same FMA statement shape / k-order). ----
__global__ __launch_bounds__(256)
void score_kernel(const float* __restrict__ qT, const float* __restrict__ kT,
                  const u64* __restrict__ mbits, float* __restrict__ sbuf,
                  float* __restrict__ segmax, int sl0) {
  __shared__ float Qs[64][128];
  __shared__ float Ks[64][128];
  const int sl = sl0 + blockIdx.z;
  const int b = sl >> 3, h = sl & 7;
  const int s0 = blockIdx.x << 7, q0 = blockIdx.y << 7;
  const int tid = threadIdx.x;
  const float* qbase = qT + (size_t)sl * 64 * 2048 + q0;
  const float* kbase = kT + (size_t)h * 64 * 4096 + s0;
  float4* Qf = (float4*)&Qs[0][0];
  float4* Kf = (float4*)&Ks[0][0];
#pragma unroll
  for (int u = 0; u < 8; ++u) {
    int i = (u << 8) + tid;
    int row = i >> 5, col = (i & 31) << 2;
    Qf[i] = *(const float4*)(qbase + (size_t)row * 2048 + col);
    Kf[i] = *(const float4*)(kbase + (size_t)row * 4096 + col);
  }
  __syncthreads();
  const int tx = tid & 15, ty = tid >> 4;
  float c[8][8] = {};
#pragma unroll 4
  for (int g = 0; g < 16; ++g) {
    const int kk = g << 2;
    float qa[8][4], kb[8][4];
#pragma unroll
    for (int t = 0; t < 4; ++t) {
#pragma unroll
      for (int i = 0; i < 8; ++i) qa[i][t] = Qs[kk + t][(ty << 3) + i];
#pragma unroll
      for (int j = 0; j < 4; ++j) {
        kb[j][t]     = Ks[kk + t][(tx << 2) + j];
        kb[4 + j][t] = Ks[kk + t][64 + (tx << 2) + j];
      }
    }
#pragma unroll
    for (int i = 0; i < 8; ++i)
#pragma unroll
      for (int j = 0; j < 8; ++j)
        c[i][j] += qa[i][0] * kb[j][0] + qa[i][1] * kb[j][1]
                 + qa[i][2] * kb[j][2] + qa[i][3] * kb[j][3];
  }
  float* srow = sbuf + ((size_t)blockIdx.z * 2048 + q0) * 4096 + s0;
  const u64* mrow = mbits + ((size_t)(b * 2048 + q0)) * 64 + (s0 >> 6);
#pragma unroll
  for (int i = 0; i < 8; ++i) {
    const int row = (ty << 3) + i;
    u64 wA = mrow[(size_t)row * 64];
    u64 wB = mrow[(size_t)row * 64 + 1];
    float4 o0, o1;
    o0.x = ((wA >> ((tx << 2) + 0)) & 1) ? c[i][0] * 0.125f : NEGV;
    o0.y = ((wA >> ((tx << 2) + 1)) & 1) ? c[i][1] * 0.125f : NEGV;
    o0.z = ((wA >> ((tx << 2) + 2)) & 1) ? c[i][2] * 0.125f : NEGV;
    o0.w = ((wA >> ((tx << 2) + 3)) & 1) ? c[i][3] * 0.125f : NEGV;
    o1.x = ((wB >> ((tx << 2) + 0)) & 1) ? c[i][4] * 0.125f : NEGV;
    o1.y = ((wB >> ((tx << 2) + 1)) & 1) ? c[i][5] * 0.125f : NEGV;
    o1.z = ((wB >> ((tx << 2) + 2)) & 1) ? c[i][6] * 0.125f : NEGV;
    o1.w = ((wB >> ((tx << 2) + 3)) & 1) ? c[i][7] * 0.125f : NEGV;
    *(float4*)&srow[(size_t)row * 4096 + (tx << 2)] = o0;
    *(float4*)&srow[(size_t)row * 4096 + 64 + (tx << 2)] = o1;
    // 32-wide segment maxes: tx<8 covers s-local [0,32)/[64,96); tx>=8 the others
    float m0 = fmaxf(fmaxf(o0.x, o0.y), fmaxf(o0.z, o0.w));
    float m1 = fmaxf(fmaxf(o1.x, o1.y), fmaxf(o1.z, o1.w));
#pragma unroll
    for (int off = 4; off; off >>= 1) {
      m0 = fmaxf(m0, __shfl_xor(m0, off, 64));
      m1 = fmaxf(m1, __shfl_xor(m1, off, 64));
    }
    if ((tx & 7) == 0) {
      size_t sg = ((size_t)blockIdx.z * 2048 + q0 + row) * 128 + (s0 >> 5) + (tx >> 3);
      segmax[sg] = m0;
      segmax[sg + 2] = m1;
    }
  }
}

// ---- fused top-k + softmax + ctx: one WAVE per q-row (4 waves/block).
// T = 64th-largest of the 128 segmaxes (provable lower bound on the 64th-
// largest element). Lanes load their two contiguous 32-float segments only
// if segmax >= T; candidates (x >= T) -> per-lane LDS slots; binary search
// reads u32 ords only (register-light); extraction re-reads u64 from LDS. ----
__global__ __launch_bounds__(256)
void topk_ctx_kernel(const float* __restrict__ sbuf, const float* __restrict__ segmax,
                     const float* __restrict__ vbuf, float* __restrict__ ctxbuf,
                     int sl0) {
  const int sl = sl0 + blockIdx.y;
  const int b = sl >> 3, h = sl & 7;
  const int w = threadIdx.x >> 6, lane = threadIdx.x & 63;
  const int qi = (blockIdx.x << 2) + w;
  __shared__ u64 cand_lds[4][NCAND][64];   // 32 KB/block
  u64* list = &cand_lds[w][0][0];
  const u64 lmask_lt = (1ull << lane) - 1ull;
  const u32 ordneg = f2ord(NEGV);

  const float* srow = sbuf + ((size_t)blockIdx.y * 2048 + qi) * 4096;

  // segment maxes: 2 per lane (lane's own contiguous 64-elem region)
  float2 smv = *(const float2*)(segmax + ((size_t)blockIdx.y * 2048 + qi) * 128 + (lane << 1));
  u32 so0 = f2ord(smv.x), so1 = f2ord(smv.y);
  u32 mxo = so0 > so1 ? so0 : so1;
  u32 mno = so0 < so1 ? so0 : so1;
#pragma unroll
  for (int off = 32; off; off >>= 1) {
    u32 a = (u32)__shfl_xor((int)mxo, off, 64);
    u32 c = (u32)__shfl_xor((int)mno, off, 64);
    mxo = a > mxo ? a : mxo;
    mno = c < mno ? c : mno;
  }
  const float fm = ord2f(mxo);
  // T = largest v with count(segmax >= v) >= 64
  {
    u32 lo = mno, hi = mxo + 1;
    while (hi - lo > 1) {
      u32 mid = lo + ((hi - lo) >> 1);
      int c = __popcll(__ballot(so0 >= mid)) + __popcll(__ballot(so1 >= mid));
      if (c >= 64) lo = mid; else hi = mid;
    }
    mno = lo;  // reuse as ordT
  }
  const u32 ordT = mno;
  const float Tf = ord2f(ordT);

  // load only segments with segmax >= T; collect candidates x >= T
  int cnt = 0;
  const float* lbase = srow + (lane << 6);
#pragma unroll
  for (int reg = 0; reg < 2; ++reg) {
    bool active = (reg == 0) ? (smv.x >= Tf) : (smv.y >= Tf);
    if (active) {
      const float* rb = lbase + (reg << 5);
      float4 v0 = *(const float4*)(rb + 0);
      float4 v1 = *(const float4*)(rb + 4);
      float4 v2 = *(const float4*)(rb + 8);
      float4 v3 = *(const float4*)(rb + 12);
      float4 v4 = *(const float4*)(rb + 16);
      float4 v5 = *(const float4*)(rb + 20);
      float4 v6 = *(const float4*)(rb + 24);
      float4 v7 = *(const float4*)(rb + 28);
      float xs[32] = {v0.x, v0.y, v0.z, v0.w, v1.x, v1.y, v1.z, v1.w,
                      v2.x, v2.y, v2.z, v2.w, v3.x, v3.y, v3.z, v3.w,
                      v4.x, v4.y, v4.z, v4.w, v5.x, v5.y, v5.z, v5.w,
                      v6.x, v6.y, v6.z, v6.w, v7.x, v7.y, v7.z, v7.w};
#pragma unroll
      for (int cc = 0; cc < 32; ++cc) {
        if (xs[cc] >= Tf) {
          if (cnt < NCAND) {
            int sidx = (lane << 6) + (reg << 5) + cc;
            cand_lds[w][cnt][lane] = ((u64)f2ord(xs[cc]) << 32) | (u32)sidx;
          }
          cnt++;
        }
      }
    }
  }
  const bool fb = (__ballot(cnt > NCAND) != 0ull);

  float esum = 0.f;
  int nsel = 0;
  bool meanpath = false;

  if (!fb) {
    // register-light search: u32 ords only (high word of each packed cand)
    u32 co[NCAND];
#pragma unroll
    for (int j = 0; j < NCAND; ++j)
      co[j] = (j < cnt) ? ((const u32*)&cand_lds[w][j][lane])[1] : 0u;
    u32 lo = ordT, hi = mxo + 1;
    while (hi - lo > 1) {
      u32 mid = lo + ((hi - lo) >> 1);
      int c = 0;
#pragma unroll
      for (int j = 0; j < NCAND; ++j)
        c += __popcll(__ballot(co[j] >= mid));
      if (c >= 64) lo = mid; else hi = mid;
    }
    // extraction: re-read u64 from LDS in the same j-order
    int base = 0;
#pragma unroll
    for (int j = 0; j < NCAND; ++j) {
      bool pred = (j < cnt) && (co[j] >= lo);
      u64 m = __ballot(pred);
      int ofs = base + __popcll(m & lmask_lt);
      if (pred && ofs < LISTCAP) {
        u64 cj = cand_lds[w][j][lane];
        float ev = __expf(ord2f((u32)(cj >> 32)) - fm);
        list[ofs] = ((u64)((u32)cj) << 32) | (u64)__float_as_uint(ev);
        esum += ev;
      }
      base += (int)__popcll(m);
    }
    nsel = base < LISTCAP ? base : LISTCAP;
  } else {
    // rare exact fallback: full binary search streaming the row (L2/L3-hot)
    u32 lo = ordT, hi = mxo + 1;
    while (hi - lo > 1) {
      u32 mid = lo + ((hi - lo) >> 1);
      float midf = ord2f(mid);
      int c = 0;
      for (int j = 0; j < 16; ++j) {
        float4 v = *(const float4*)(srow + (j << 8) + (lane << 2));
        c += __popcll(__ballot(v.x >= midf)) + __popcll(__ballot(v.y >= midf)) +
             __popcll(__ballot(v.z >= midf)) + __popcll(__ballot(v.w >= midf));
      }
      if (c >= 64) lo = mid; else hi = mid;
    }
    const float thrf = ord2f(lo);
    int base = 0;
    for (int j = 0; j < 16; ++j) {
      float4 v = *(const float4*)(srow + (j << 8) + (lane << 2));
      float xs[4] = {v.x, v.y, v.z, v.w};
#pragma unroll
      for (int cpos = 0; cpos < 4; ++cpos) {
        float x = xs[cpos];
        bool pred = (x >= thrf) && (x != NEGV);
        u64 m = __ballot(pred);
        int ofs = base + __popcll(m & lmask_lt);
        if (pred && ofs < LISTCAP) {
          int sidx = (j << 8) + (lane << 2) + cpos;
          float ev = __expf(x - fm);
          list[ofs] = ((u64)(u32)sidx << 32) | (u64)__float_as_uint(ev);
          esum += ev;
        }
        base += (int)__popcll(m);
      }
    }
    nsel = base < LISTCAP ? base : LISTCAP;
    if (base == 0) meanpath = true;  // fully masked row
  }

#pragma unroll
  for (int off = 32; off; off >>= 1) esum += __shfl_xor(esum, off, 64);
  const float* vb = vbuf + h * 64 + lane;
  float outv;
  if (!meanpath) {
    const float rs = 1.0f / esum;
    int pad = (8 - (nsel & 7)) & 7;
    if (lane < pad && nsel + lane < LISTCAP) list[nsel + lane] = 0;  // ev=+0, idx=0
    int n8 = nsel + pad;
    if (n8 > LISTCAP) n8 = LISTCAP;
    float a0 = 0.f, a1 = 0.f, a2 = 0.f, a3 = 0.f;
    float a4 = 0.f, a5 = 0.f, a6 = 0.f, a7 = 0.f;
    for (int g = 0; g < n8; g += 8) {
      u64 p0 = list[g + 0], p1 = list[g + 1], p2 = list[g + 2], p3 = list[g + 3];
      u64 p4 = list[g + 4], p5 = list[g + 5], p6 = list[g + 6], p7 = list[g + 7];
      a0 += __uint_as_float((u32)p0) * vb[(size_t)(p0 >> 32) * 512];
      a1 += __uint_as_float((u32)p1) * vb[(size_t)(p1 >> 32) * 512];
      a2 += __uint_as_float((u32)p2) * vb[(size_t)(p2 >> 32) * 512];
      a3 += __uint_as_float((u32)p3) * vb[(size_t)(p3 >> 32) * 512];
      a4 += __uint_as_float((u32)p4) * vb[(size_t)(p4 >> 32) * 512];
      a5 += __uint_as_float((u32)p5) * vb[(size_t)(p5 >> 32) * 512];
      a6 += __uint_as_float((u32)p6) * vb[(size_t)(p6 >> 32) * 512];
      a7 += __uint_as_float((u32)p7) * vb[(size_t)(p7 >> 32) * 512];
    }
    outv = (((a0 + a1) + (a2 + a3)) + ((a4 + a5) + (a6 + a7))) * rs;
  } else {
    float acc = 0.f;
    for (int s = 0; s < 4096; ++s) acc += vb[(size_t)s * 512];
    outv = acc * (1.0f / 4096.0f);
  }
  ctxbuf[((size_t)(b * 2048 + qi)) * 512 + h * 64 + lane] = outv;
}

extern "C" void kernel_launch(void* const* d_in, const int* in_sizes, int n_in,
                              void* d_out, int out_size, void* d_ws, size_t ws_size,
                              hipStream_t stream) {
  const float* main_in = (const float*)d_in[0];
  const float* side_in = (const float*)d_in[1];
  const int*   mask    = (const int*)d_in[2];
  const float* Wq = (const float*)d_in[3];
  const float* bq = (const float*)d_in[4];
  const float* Wk = (const float*)d_in[5];
  const float* bk = (const float*)d_in[6];
  const float* Wv = (const float*)d_in[7];
  const float* bv = (const float*)d_in[8];
  const float* Wo = (const float*)d_in[9];
  const float* bo = (const float*)d_in[10];
  float* out = (float*)d_out;

  char* ws = (char*)d_ws;
  float* qT   = (float*)(ws);                       // 8 MB
  float* kT   = (float*)(ws + ((size_t)8 << 20));   // 8 MB
  float* vbuf = (float*)(ws + ((size_t)16 << 20));  // 8 MB
  float* ctxb = (float*)(ws + ((size_t)24 << 20));  // 8 MB
  u64* mbits  = (u64*)(ws + ((size_t)32 << 20));    // 2 MB
  const size_t base = (size_t)34 << 20;
  const size_t sliceb = (size_t)2048 * 4096 * 4;    // 32 MB scores/slice
  const size_t segb   = (size_t)2048 * 128 * 4;     // 1 MB segmax/slice
  const size_t per = sliceb + segb;

  // cap nz at 4 so the slice working set (~132 MB) stays L3-resident
  int nz = 1;
  if (ws_size > base + per) {
    size_t m = (ws_size - base) / per;
    nz = (int)(m > 4 ? 4 : m);
  }
  float* sbuf = (float*)(ws + base);
  float* smax = (float*)(ws + base + (size_t)nz * sliceb);

  pack_mask<<<1024, 256, 0, stream>>>(mask, mbits);
  gemm_bias_T<<<dim3(8, 64), 256, 0, stream>>>(main_in, Wq, bq, qT, 11);
  gemm_bias_T<<<dim3(8, 64), 256, 0, stream>>>(side_in, Wk, bk, kT, 12);
  gemm_bias  <<<dim3(8, 64), 256, 0, stream>>>(side_in, Wv, bv, vbuf);

  for (int sl0 = 0; sl0 < 16; sl0 += nz) {
    int z = nz < (16 - sl0) ? nz : (16 - sl0);
    score_kernel   <<<dim3(32, 16, z), 256, 0, stream>>>(qT, kT, mbits, sbuf, smax, sl0);
    topk_ctx_kernel<<<dim3(512, z), 256, 0, stream>>>(sbuf, smax, vbuf, ctxb, sl0);
  }

  gemm_bias<<<dim3(8, 64), 256, 0, stream>>>(ctxb, Wo, bo, out);
}